// Round 1
// baseline (30695.935 us; speedup 1.0000x reference)
//
#include <hip/hip_runtime.h>

// Decoder: emb -> 3-layer GRU -> scaled-dot attention over encoder -> tanh(linear) -> logits
// Round 0: correct-first. bf16 MFMA GEMMs w/ fp32 accum; fp32 h/gates/softmax.
// Known inefficiency: 1536 per-step GRU launches (launch-bound) - measured this round.

typedef unsigned short u16;
typedef __attribute__((ext_vector_type(8))) __bf16 bf16x8;
typedef __attribute__((ext_vector_type(4))) float f32x4;
typedef __attribute__((ext_vector_type(4))) unsigned int u32x4;

#define D_ 512
#define S_ 512
#define SE_ 512
#define B_ 128
#define V_ 100
#define TD_ 1536

__device__ __forceinline__ float bf2f(u16 v) {
  unsigned u = ((unsigned)v) << 16;
  return __builtin_bit_cast(float, u);
}
__device__ __forceinline__ u16 f2bf(float f) {
  unsigned u = __builtin_bit_cast(unsigned, f);
  u += 0x7FFF + ((u >> 16) & 1);   // RNE
  return (u16)(u >> 16);
}

// ---------------- elementwise converts / copies ----------------
__global__ __launch_bounds__(256) void cvt_f32_bf16(const float* __restrict__ src,
                                                    u16* __restrict__ dst, long n4) {
  long i = (long)blockIdx.x * 256 + threadIdx.x;
  long stride = (long)gridDim.x * 256;
  for (; i < n4; i += stride) {
    float4 v = ((const float4*)src)[i];
    unsigned long long p = (unsigned long long)f2bf(v.x) |
                           ((unsigned long long)f2bf(v.y) << 16) |
                           ((unsigned long long)f2bf(v.z) << 32) |
                           ((unsigned long long)f2bf(v.w) << 48);
    ((unsigned long long*)dst)[i] = p;
  }
}

__global__ __launch_bounds__(256) void copy_f32(const float* __restrict__ s,
                                                float* __restrict__ d, int n) {
  int i = blockIdx.x * 256 + threadIdx.x;
  if (i < n) d[i] = s[i];
}

__global__ __launch_bounds__(256) void embed_gather(const int* __restrict__ tok,
                                                    const float* __restrict__ table,
                                                    u16* __restrict__ out) {
  long i = (long)blockIdx.x * 256 + threadIdx.x;
  long stride = (long)gridDim.x * 256;
  const long tot = 65536L * 128;      // (B*S) rows * 128 float4-groups
  for (; i < tot; i += stride) {
    long row = i >> 7;
    int dq = (int)(i & 127);
    int t = tok[row];
    float4 v = ((const float4*)(table + (long)t * D_))[dq];
    unsigned long long p = (unsigned long long)f2bf(v.x) |
                           ((unsigned long long)f2bf(v.y) << 16) |
                           ((unsigned long long)f2bf(v.z) << 32) |
                           ((unsigned long long)f2bf(v.w) << 48);
    ((unsigned long long*)(out + row * D_))[dq] = p;
  }
}

// enc (B,SE,D) f32 -> encT (B,D,SE) bf16
__global__ __launch_bounds__(256) void transpose_enc(const float* __restrict__ enc,
                                                     u16* __restrict__ encT) {
  __shared__ u16 tile[64][72];
  int b = blockIdx.z, d0 = blockIdx.x * 64, se0 = blockIdx.y * 64;
  const float* src = enc + (long)b * SE_ * D_;
  int t = threadIdx.x;
  int r = t >> 2, cq = (t & 3) * 16;
#pragma unroll
  for (int j = 0; j < 4; ++j) {
    float4 v = *(const float4*)(src + (long)(se0 + r) * D_ + d0 + cq + j * 4);
    tile[r][cq + j * 4 + 0] = f2bf(v.x);
    tile[r][cq + j * 4 + 1] = f2bf(v.y);
    tile[r][cq + j * 4 + 2] = f2bf(v.z);
    tile[r][cq + j * 4 + 3] = f2bf(v.w);
  }
  __syncthreads();
  u16* dst = encT + (long)b * D_ * SE_;
  u16 ov[16];
#pragma unroll
  for (int j = 0; j < 16; ++j) ov[j] = tile[cq + j][r];
  *(u32x4*)(dst + (long)(d0 + r) * SE_ + se0 + cq) = *(u32x4*)&ov[0];
  *(u32x4*)(dst + (long)(d0 + r) * SE_ + se0 + cq + 8) = *(u32x4*)&ov[8];
}

// in-place fp32 softmax over 512-wide rows + bf16 copy
__global__ __launch_bounds__(256) void softmax_rows(float* __restrict__ sc,
                                                    u16* __restrict__ abf) {
  long row = (long)blockIdx.x * 4 + (threadIdx.x >> 6);
  int lane = threadIdx.x & 63;
  float* p = sc + row * 512;
  float4 v0 = ((const float4*)p)[lane * 2];
  float4 v1 = ((const float4*)p)[lane * 2 + 1];
  float vals[8] = {v0.x, v0.y, v0.z, v0.w, v1.x, v1.y, v1.z, v1.w};
  float m = vals[0];
#pragma unroll
  for (int j = 1; j < 8; ++j) m = fmaxf(m, vals[j]);
#pragma unroll
  for (int o = 32; o; o >>= 1) m = fmaxf(m, __shfl_xor(m, o, 64));
  float s = 0.f;
#pragma unroll
  for (int j = 0; j < 8; ++j) { vals[j] = __expf(vals[j] - m); s += vals[j]; }
#pragma unroll
  for (int o = 32; o; o >>= 1) s += __shfl_xor(s, o, 64);
  float inv = 1.f / s;
  u16 ob[8];
#pragma unroll
  for (int j = 0; j < 8; ++j) { vals[j] *= inv; ob[j] = f2bf(vals[j]); }
  float4 w0 = {vals[0], vals[1], vals[2], vals[3]};
  float4 w1 = {vals[4], vals[5], vals[6], vals[7]};
  ((float4*)p)[lane * 2] = w0;
  ((float4*)p)[lane * 2 + 1] = w1;
  *(u32x4*)(abf + row * 512 + lane * 8) = *(u32x4*)ob;
}

// ---------------- generic C = A(M,K) @ W(N,K)^T, bf16 in / f32 acc ----------------
// MODE 0: +bias -> bf16 (xp)        MODE 1: *scale -> f32 batched (scores)
// MODE 2: -> bf16 batched (context) MODE 3: split-K A, tanh(+bias)*mask -> bf16
// MODE 4: (+bias)*mask -> f32, col<N (logits)
template <int MODE>
__global__ __launch_bounds__(256) void gemm_xwt(
    const u16* __restrict__ A1, const u16* __restrict__ A2, const u16* __restrict__ W,
    const float* __restrict__ bias, void* __restrict__ Cout, const u16* __restrict__ maskSrc,
    int N, int K, int K1, long sAb, long sWb, long sCb, float scale, int ldc) {
  __shared__ u16 sA[128][32];
  __shared__ u16 sW_[128][32];
  int bz = blockIdx.z;
  int n0 = blockIdx.x * 128, m0 = blockIdx.y * 128;
  const u16* Ab = A1 + (long)bz * sAb;
  const u16* Wb = W + (long)bz * sWb;
  int t = threadIdx.x, wave = t >> 6, lane = t & 63;
  int wm = (wave >> 1) * 64, wn = (wave & 1) * 64;
  f32x4 acc[4][4] = {};
  for (int kk = 0; kk < K; kk += 32) {
#pragma unroll
    for (int i = 0; i < 2; ++i) {
      int id = t + i * 256;
      int row = id >> 2, c8 = (id & 3) * 8;
      const u16* src;
      if (MODE == 3 && kk >= K1)
        src = A2 + (long)(m0 + row) * (K - K1) + (kk - K1) + c8;
      else
        src = Ab + (long)(m0 + row) * K1 + kk + c8;
      *(u32x4*)&sA[row][c8] = *(const u32x4*)src;
    }
#pragma unroll
    for (int i = 0; i < 2; ++i) {
      int id = t + i * 256;
      int row = id >> 2, c8 = (id & 3) * 8;
      u32x4 v = {0u, 0u, 0u, 0u};
      if (n0 + row < N) v = *(const u32x4*)(Wb + (long)(n0 + row) * K + kk + c8);
      *(u32x4*)&sW_[row][c8] = v;
    }
    __syncthreads();
    int k8 = (lane >> 4) * 8, rr = lane & 15;
    bf16x8 wf[4];
#pragma unroll
    for (int nt = 0; nt < 4; ++nt)
      wf[nt] = __builtin_bit_cast(bf16x8, *(const u32x4*)&sW_[wn + nt * 16 + rr][k8]);
#pragma unroll
    for (int mt = 0; mt < 4; ++mt) {
      bf16x8 af = __builtin_bit_cast(bf16x8, *(const u32x4*)&sA[wm + mt * 16 + rr][k8]);
#pragma unroll
      for (int nt = 0; nt < 4; ++nt)
        acc[mt][nt] = __builtin_amdgcn_mfma_f32_16x16x32_bf16(af, wf[nt], acc[mt][nt], 0, 0, 0);
    }
    __syncthreads();
  }
  int rq = (lane >> 4) * 4, cl = lane & 15;
#pragma unroll
  for (int mt = 0; mt < 4; ++mt) {
#pragma unroll
    for (int nt = 0; nt < 4; ++nt) {
#pragma unroll
      for (int rg = 0; rg < 4; ++rg) {
        int row = m0 + wm + mt * 16 + rq + rg;
        int col = n0 + wn + nt * 16 + cl;
        float v = acc[mt][nt][rg];
        if (MODE == 0) {
          ((u16*)Cout)[(long)row * ldc + col] = f2bf(v + bias[col]);
        } else if (MODE == 1) {
          ((float*)Cout)[(long)bz * sCb + (long)row * ldc + col] = v * scale;
        } else if (MODE == 2) {
          ((u16*)Cout)[(long)bz * sCb + (long)row * ldc + col] = f2bf(v);
        } else if (MODE == 3) {
          float mk = (bf2f(maskSrc[(long)row * D_]) != 0.f) ? 1.f : 0.f;
          ((u16*)Cout)[(long)row * ldc + col] = f2bf(tanhf(v + bias[col]) * mk);
        } else {
          if (col < N) {
            float mk = (bf2f(maskSrc[(long)row * D_]) != 0.f) ? 1.f : 0.f;
            ((float*)Cout)[(long)row * ldc + col] = (v + bias[col]) * mk;
          }
        }
      }
    }
  }
}

// ---------------- one GRU timestep: gh = h @ Whh^T, fused gates ----------------
// grid (8 ch-chunks, 2 batch-chunks), 256 threads. h fp32 ping-pong; x out bf16.
__global__ __launch_bounds__(256) void gru_step(
    const u16* __restrict__ xp, const u16* __restrict__ whh, const float* __restrict__ bhh,
    const float* __restrict__ hin, float* __restrict__ hout, u16* __restrict__ xout, int tt) {
  __shared__ u16 sH[64][32];
  __shared__ u16 sW[192][32];
  int d0 = blockIdx.x * 64;
  int b0 = blockIdx.y * 64;
  int t = threadIdx.x, wave = t >> 6, lane = t & 63;
  f32x4 acc[3][4] = {};
  for (int kk = 0; kk < 512; kk += 32) {
    {
      int row = t >> 2, c8 = (t & 3) * 8;
      const float* src = hin + (long)(b0 + row) * 512 + kk + c8;
      float4 va = *(const float4*)src;
      float4 vb = *(const float4*)(src + 4);
      u16 tmp[8] = {f2bf(va.x), f2bf(va.y), f2bf(va.z), f2bf(va.w),
                    f2bf(vb.x), f2bf(vb.y), f2bf(vb.z), f2bf(vb.w)};
      *(u32x4*)&sH[row][c8] = *(u32x4*)tmp;
    }
#pragma unroll
    for (int i = 0; i < 3; ++i) {
      int id = t + i * 256;
      int row = id >> 2, c8 = (id & 3) * 8;
      int g = row >> 6, ch = row & 63;
      *(u32x4*)&sW[row][c8] = *(const u32x4*)(whh + (long)(g * 512 + d0 + ch) * 512 + kk + c8);
    }
    __syncthreads();
    int k8 = (lane >> 4) * 8, rr = lane & 15;
    bf16x8 af = __builtin_bit_cast(bf16x8, *(const u32x4*)&sH[wave * 16 + rr][k8]);
#pragma unroll
    for (int g = 0; g < 3; ++g)
#pragma unroll
      for (int nt = 0; nt < 4; ++nt) {
        bf16x8 wf = __builtin_bit_cast(bf16x8, *(const u32x4*)&sW[g * 64 + nt * 16 + rr][k8]);
        acc[g][nt] = __builtin_amdgcn_mfma_f32_16x16x32_bf16(af, wf, acc[g][nt], 0, 0, 0);
      }
    __syncthreads();
  }
  int rq = (lane >> 4), cl = lane & 15;
#pragma unroll
  for (int nt = 0; nt < 4; ++nt) {
#pragma unroll
    for (int rg = 0; rg < 4; ++rg) {
      int bb = b0 + wave * 16 + rq * 4 + rg;
      int ch = d0 + nt * 16 + cl;
      long xprow = ((long)bb * S_ + tt) * (long)TD_;
      float xr = bf2f(xp[xprow + ch]);
      float xz = bf2f(xp[xprow + 512 + ch]);
      float xn = bf2f(xp[xprow + 1024 + ch]);
      float hr = acc[0][nt][rg] + bhh[ch];
      float hz = acc[1][nt][rg] + bhh[512 + ch];
      float hn = acc[2][nt][rg] + bhh[1024 + ch];
      float r = 1.f / (1.f + __expf(-(xr + hr)));
      float z = 1.f / (1.f + __expf(-(xz + hz)));
      float n = tanhf(xn + r * hn);
      float hold = hin[(long)bb * 512 + ch];
      float h2 = (1.f - z) * n + z * hold;
      hout[(long)bb * 512 + ch] = h2;
      xout[((long)bb * S_ + tt) * (long)D_ + ch] = f2bf(h2);
    }
  }
}

extern "C" void kernel_launch(void* const* d_in, const int* in_sizes, int n_in,
                              void* d_out, int out_size, void* d_ws, size_t ws_size,
                              hipStream_t stream) {
  const int* padded    = (const int*)d_in[0];
  const float* enc     = (const float*)d_in[2];
  const float* hidden  = (const float*)d_in[3];
  const float* embedding = (const float*)d_in[4];
  const float* w_ih    = (const float*)d_in[5];
  const float* w_hh    = (const float*)d_in[6];
  const float* b_ih    = (const float*)d_in[7];
  const float* b_hh    = (const float*)d_in[8];
  const float* attn_w  = (const float*)d_in[9];
  const float* attn_b  = (const float*)d_in[10];
  const float* out_w   = (const float*)d_in[11];
  const float* out_b   = (const float*)d_in[12];

  if (ws_size < 346656768ULL) return;   // ws budget guard

  char* ws = (char*)d_ws;
  u16* W_IH   = (u16*)(ws + 0);             // 3*1536*512 bf16
  u16* W_HH   = (u16*)(ws + 4718592);
  u16* ATTN_W = (u16*)(ws + 9437184);       // 512*1024
  u16* OUT_W  = (u16*)(ws + 10485760);      // 100*512
  float* HB0  = (float*)(ws + 10588160);    // 128*512 f32
  float* HB1  = (float*)(ws + 10850304);
  u16* XA     = (u16*)(ws + 11112448);      // 65536*512 bf16
  u16* XB     = (u16*)(ws + 78221312);
  u16* XP     = (u16*)(ws + 145330176);     // 65536*1536 bf16
  u16* ATTN_BF = XP;                        // aliases (post-GRU)
  u16* ENC_BF  = (u16*)(ws + 145330176 + 67108864);
  u16* ENCT    = ENC_BF;
  u16* AMASK   = (u16*)(ws + 145330176 + 134217728);

  float* out_logits = (float*)d_out;                 // 65536*100
  float* out_h      = out_logits + 6553600;          // 3*128*512
  float* out_attn   = out_h + 196608;                // 128*512*512

  cvt_f32_bf16<<<512, 256, 0, stream>>>(w_ih, W_IH, 2359296 / 4);
  cvt_f32_bf16<<<512, 256, 0, stream>>>(w_hh, W_HH, 2359296 / 4);
  cvt_f32_bf16<<<256, 256, 0, stream>>>(attn_w, ATTN_W, 524288 / 4);
  cvt_f32_bf16<<<64, 256, 0, stream>>>(out_w, OUT_W, 51200 / 4);
  embed_gather<<<2048, 256, 0, stream>>>(padded, embedding, XA);

  for (int l = 0; l < 3; ++l) {
    const u16* xin = (l == 1) ? XB : XA;
    u16* xout = (l == 1) ? XA : XB;
    copy_f32<<<256, 256, 0, stream>>>(hidden + l * 65536, HB0, 65536);
    gemm_xwt<0><<<dim3(12, 512, 1), 256, 0, stream>>>(
        xin, nullptr, W_IH + l * 786432, b_ih + l * 1536, XP, nullptr,
        1536, 512, 512, 0, 0, 0, 1.f, 1536);
    for (int tt = 0; tt < 512; ++tt) {
      const float* hi = (tt & 1) ? HB1 : HB0;
      float* ho = (tt & 1) ? HB0 : HB1;
      gru_step<<<dim3(8, 2, 1), 256, 0, stream>>>(
          XP, W_HH + l * 786432, b_hh + l * 1536, hi, ho, xout, tt);
    }
    copy_f32<<<256, 256, 0, stream>>>(HB0, out_h + l * 65536, 65536);
  }

  // attention
  cvt_f32_bf16<<<2048, 256, 0, stream>>>(enc, ENC_BF, 33554432 / 4);
  gemm_xwt<1><<<dim3(4, 4, 128), 256, 0, stream>>>(
      XB, nullptr, ENC_BF, nullptr, out_attn, nullptr,
      512, 512, 512, 262144, 262144, 262144, 0.044194173824159216f, 512);
  softmax_rows<<<16384, 256, 0, stream>>>(out_attn, ATTN_BF);
  transpose_enc<<<dim3(8, 8, 128), 256, 0, stream>>>(enc, ENCT);
  gemm_xwt<2><<<dim3(4, 4, 128), 256, 0, stream>>>(
      ATTN_BF, nullptr, ENCT, nullptr, XA, nullptr,
      512, 512, 512, 262144, 262144, 262144, 1.f, 512);
  gemm_xwt<3><<<dim3(4, 512, 1), 256, 0, stream>>>(
      XB, XA, ATTN_W, attn_b, AMASK, XB,
      512, 1024, 512, 0, 0, 0, 1.f, 512);
  gemm_xwt<4><<<dim3(1, 512, 1), 256, 0, stream>>>(
      AMASK, nullptr, OUT_W, out_b, d_out, XB,
      100, 512, 512, 0, 0, 0, 1.f, 100);
}

// Round 2
// 11593.346 us; speedup vs baseline: 2.6477x; 2.6477x over previous
//
#include <hip/hip_runtime.h>

// Decoder: emb -> 3-layer GRU -> scaled-dot attention over encoder -> tanh(linear) -> logits
// Round 1: persistent per-layer GRU kernel (3 launches instead of 1536).
//   - Whh register-resident (48 frags/thread, ~200 VGPR, launch_bounds(256,1))
//   - fp32 h master in regs; bf16 h exchanged via double-buffered global buffer
//   - batch-group-local flag sync (4 bg x 16 cg WGs), agent-scope acq/rel atomics
//   - xp[t] prefetched into regs before the flag spin

typedef unsigned short u16;
typedef __attribute__((ext_vector_type(8))) __bf16 bf16x8;
typedef __attribute__((ext_vector_type(4))) float f32x4;
typedef __attribute__((ext_vector_type(4))) unsigned int u32x4;

#define D_ 512
#define S_ 512
#define SE_ 512
#define B_ 128
#define V_ 100
#define TD_ 1536
#define NBG 4
#define NCG 16

__device__ __forceinline__ float bf2f(u16 v) {
  unsigned u = ((unsigned)v) << 16;
  return __builtin_bit_cast(float, u);
}
__device__ __forceinline__ u16 f2bf(float f) {
  unsigned u = __builtin_bit_cast(unsigned, f);
  u += 0x7FFF + ((u >> 16) & 1);   // RNE
  return (u16)(u >> 16);
}

// ---------------- elementwise converts / copies ----------------
__global__ __launch_bounds__(256) void cvt_f32_bf16(const float* __restrict__ src,
                                                    u16* __restrict__ dst, long n4) {
  long i = (long)blockIdx.x * 256 + threadIdx.x;
  long stride = (long)gridDim.x * 256;
  for (; i < n4; i += stride) {
    float4 v = ((const float4*)src)[i];
    unsigned long long p = (unsigned long long)f2bf(v.x) |
                           ((unsigned long long)f2bf(v.y) << 16) |
                           ((unsigned long long)f2bf(v.z) << 32) |
                           ((unsigned long long)f2bf(v.w) << 48);
    ((unsigned long long*)dst)[i] = p;
  }
}

__global__ __launch_bounds__(256) void zero_flags(unsigned* __restrict__ f, int n) {
  int i = blockIdx.x * 256 + threadIdx.x;
  if (i < n) f[i] = 0;
}

__global__ __launch_bounds__(256) void embed_gather(const int* __restrict__ tok,
                                                    const float* __restrict__ table,
                                                    u16* __restrict__ out) {
  long i = (long)blockIdx.x * 256 + threadIdx.x;
  long stride = (long)gridDim.x * 256;
  const long tot = 65536L * 128;      // (B*S) rows * 128 float4-groups
  for (; i < tot; i += stride) {
    long row = i >> 7;
    int dq = (int)(i & 127);
    int t = tok[row];
    float4 v = ((const float4*)(table + (long)t * D_))[dq];
    unsigned long long p = (unsigned long long)f2bf(v.x) |
                           ((unsigned long long)f2bf(v.y) << 16) |
                           ((unsigned long long)f2bf(v.z) << 32) |
                           ((unsigned long long)f2bf(v.w) << 48);
    ((unsigned long long*)(out + row * D_))[dq] = p;
  }
}

// enc (B,SE,D) f32 -> encT (B,D,SE) bf16
__global__ __launch_bounds__(256) void transpose_enc(const float* __restrict__ enc,
                                                     u16* __restrict__ encT) {
  __shared__ u16 tile[64][72];
  int b = blockIdx.z, d0 = blockIdx.x * 64, se0 = blockIdx.y * 64;
  const float* src = enc + (long)b * SE_ * D_;
  int t = threadIdx.x;
  int r = t >> 2, cq = (t & 3) * 16;
#pragma unroll
  for (int j = 0; j < 4; ++j) {
    float4 v = *(const float4*)(src + (long)(se0 + r) * D_ + d0 + cq + j * 4);
    tile[r][cq + j * 4 + 0] = f2bf(v.x);
    tile[r][cq + j * 4 + 1] = f2bf(v.y);
    tile[r][cq + j * 4 + 2] = f2bf(v.z);
    tile[r][cq + j * 4 + 3] = f2bf(v.w);
  }
  __syncthreads();
  u16* dst = encT + (long)b * D_ * SE_;
  u16 ov[16];
#pragma unroll
  for (int j = 0; j < 16; ++j) ov[j] = tile[cq + j][r];
  *(u32x4*)(dst + (long)(d0 + r) * SE_ + se0 + cq) = *(u32x4*)&ov[0];
  *(u32x4*)(dst + (long)(d0 + r) * SE_ + se0 + cq + 8) = *(u32x4*)&ov[8];
}

// in-place fp32 softmax over 512-wide rows + bf16 copy
__global__ __launch_bounds__(256) void softmax_rows(float* __restrict__ sc,
                                                    u16* __restrict__ abf) {
  long row = (long)blockIdx.x * 4 + (threadIdx.x >> 6);
  int lane = threadIdx.x & 63;
  float* p = sc + row * 512;
  float4 v0 = ((const float4*)p)[lane * 2];
  float4 v1 = ((const float4*)p)[lane * 2 + 1];
  float vals[8] = {v0.x, v0.y, v0.z, v0.w, v1.x, v1.y, v1.z, v1.w};
  float m = vals[0];
#pragma unroll
  for (int j = 1; j < 8; ++j) m = fmaxf(m, vals[j]);
#pragma unroll
  for (int o = 32; o; o >>= 1) m = fmaxf(m, __shfl_xor(m, o, 64));
  float s = 0.f;
#pragma unroll
  for (int j = 0; j < 8; ++j) { vals[j] = __expf(vals[j] - m); s += vals[j]; }
#pragma unroll
  for (int o = 32; o; o >>= 1) s += __shfl_xor(s, o, 64);
  float inv = 1.f / s;
  u16 ob[8];
#pragma unroll
  for (int j = 0; j < 8; ++j) { vals[j] *= inv; ob[j] = f2bf(vals[j]); }
  float4 w0 = {vals[0], vals[1], vals[2], vals[3]};
  float4 w1 = {vals[4], vals[5], vals[6], vals[7]};
  ((float4*)p)[lane * 2] = w0;
  ((float4*)p)[lane * 2 + 1] = w1;
  *(u32x4*)(abf + row * 512 + lane * 8) = *(u32x4*)ob;
}

// ---------------- generic C = A(M,K) @ W(N,K)^T, bf16 in / f32 acc ----------------
template <int MODE>
__global__ __launch_bounds__(256) void gemm_xwt(
    const u16* __restrict__ A1, const u16* __restrict__ A2, const u16* __restrict__ W,
    const float* __restrict__ bias, void* __restrict__ Cout, const u16* __restrict__ maskSrc,
    int N, int K, int K1, long sAb, long sWb, long sCb, float scale, int ldc) {
  __shared__ u16 sA[128][32];
  __shared__ u16 sW_[128][32];
  int bz = blockIdx.z;
  int n0 = blockIdx.x * 128, m0 = blockIdx.y * 128;
  const u16* Ab = A1 + (long)bz * sAb;
  const u16* Wb = W + (long)bz * sWb;
  int t = threadIdx.x, wave = t >> 6, lane = t & 63;
  int wm = (wave >> 1) * 64, wn = (wave & 1) * 64;
  f32x4 acc[4][4] = {};
  for (int kk = 0; kk < K; kk += 32) {
#pragma unroll
    for (int i = 0; i < 2; ++i) {
      int id = t + i * 256;
      int row = id >> 2, c8 = (id & 3) * 8;
      const u16* src;
      if (MODE == 3 && kk >= K1)
        src = A2 + (long)(m0 + row) * (K - K1) + (kk - K1) + c8;
      else
        src = Ab + (long)(m0 + row) * K1 + kk + c8;
      *(u32x4*)&sA[row][c8] = *(const u32x4*)src;
    }
#pragma unroll
    for (int i = 0; i < 2; ++i) {
      int id = t + i * 256;
      int row = id >> 2, c8 = (id & 3) * 8;
      u32x4 v = {0u, 0u, 0u, 0u};
      if (n0 + row < N) v = *(const u32x4*)(Wb + (long)(n0 + row) * K + kk + c8);
      *(u32x4*)&sW_[row][c8] = v;
    }
    __syncthreads();
    int k8 = (lane >> 4) * 8, rr = lane & 15;
    bf16x8 wf[4];
#pragma unroll
    for (int nt = 0; nt < 4; ++nt)
      wf[nt] = __builtin_bit_cast(bf16x8, *(const u32x4*)&sW_[wn + nt * 16 + rr][k8]);
#pragma unroll
    for (int mt = 0; mt < 4; ++mt) {
      bf16x8 af = __builtin_bit_cast(bf16x8, *(const u32x4*)&sA[wm + mt * 16 + rr][k8]);
#pragma unroll
      for (int nt = 0; nt < 4; ++nt)
        acc[mt][nt] = __builtin_amdgcn_mfma_f32_16x16x32_bf16(af, wf[nt], acc[mt][nt], 0, 0, 0);
    }
    __syncthreads();
  }
  int rq = (lane >> 4) * 4, cl = lane & 15;
#pragma unroll
  for (int mt = 0; mt < 4; ++mt) {
#pragma unroll
    for (int nt = 0; nt < 4; ++nt) {
#pragma unroll
      for (int rg = 0; rg < 4; ++rg) {
        int row = m0 + wm + mt * 16 + rq + rg;
        int col = n0 + wn + nt * 16 + cl;
        float v = acc[mt][nt][rg];
        if (MODE == 0) {
          ((u16*)Cout)[(long)row * ldc + col] = f2bf(v + bias[col]);
        } else if (MODE == 1) {
          ((float*)Cout)[(long)bz * sCb + (long)row * ldc + col] = v * scale;
        } else if (MODE == 2) {
          ((u16*)Cout)[(long)bz * sCb + (long)row * ldc + col] = f2bf(v);
        } else if (MODE == 3) {
          float mk = (bf2f(maskSrc[(long)row * D_]) != 0.f) ? 1.f : 0.f;
          ((u16*)Cout)[(long)row * ldc + col] = f2bf(tanhf(v + bias[col]) * mk);
        } else {
          if (col < N) {
            float mk = (bf2f(maskSrc[(long)row * D_]) != 0.f) ? 1.f : 0.f;
            ((float*)Cout)[(long)row * ldc + col] = (v + bias[col]) * mk;
          }
        }
      }
    }
  }
}

// ---------------- persistent GRU layer ----------------
// grid 64 = 4 bg (32 batch rows) x 16 cg (32 h-chans -> 96 Whh rows).
// Whh frags register-resident; fp32 h master in regs; bf16 h via double-buffered
// global hbuf; per-bg flag handshake (agent scope) between the 16 cg WGs.
__global__ __launch_bounds__(256, 1) void gru_layer(
    const u16* __restrict__ xp,       // [B*S][1536] bf16
    const u16* __restrict__ whh,      // [1536][512] bf16
    const float* __restrict__ bhh,    // [1536] f32
    const float* __restrict__ hidden, // [B][512] f32 (this layer's h0)
    u16* __restrict__ hbuf,           // [2][B][512] bf16
    unsigned* __restrict__ flags,     // [NBG*NCG]
    u16* __restrict__ xout,           // [B][S][512] bf16
    float* __restrict__ hfinal) {     // [B][512] f32
  __shared__ u16 sH[32 * 512];        // swizzled h tile (32 KB)
  int bid = blockIdx.x;
  int bg = (bid & 7) >> 1;                        // XCD-friendly under round-robin
  int cg = ((bid >> 3) << 1) | (bid & 1);
  int tid = threadIdx.x;
  int wave = tid >> 6, lane = tid & 63;
  int mw = wave >> 1, nh = wave & 1;
  int rr = lane & 15, kq = lane >> 4;
  int cl = lane & 15, rq = lane >> 4;
  int ch = cg * 32 + nh * 16 + cl;                // this thread's h channel
  int b0 = bg * 32 + mw * 16 + rq * 4;            // batch base (rg 0..3)
  unsigned* bgflags = flags + bg * NCG;

  // --- load Whh B-fragments into registers (invariant over t) ---
  u32x4 wf[3][16];
#pragma unroll
  for (int g = 0; g < 3; ++g) {
    const u16* wrow = whh + ((long)(g * 512 + cg * 32 + nh * 16 + rr)) * 512 + kq * 8;
#pragma unroll
    for (int ks = 0; ks < 16; ++ks) wf[g][ks] = *(const u32x4*)(wrow + ks * 32);
  }
  float bh[3];
#pragma unroll
  for (int g = 0; g < 3; ++g) bh[g] = bhh[g * 512 + ch];

  // --- init fp32 master + publish bf16 h[-1] into buf 1 ---
  float mh[4];
#pragma unroll
  for (int rg = 0; rg < 4; ++rg) {
    mh[rg] = hidden[(long)(b0 + rg) * 512 + ch];
    hbuf[(long)(128 + b0 + rg) * 512 + ch] = f2bf(mh[rg]);
  }
  __syncthreads();
  if (tid == 0)
    __hip_atomic_store(&bgflags[cg], 1u, __ATOMIC_RELEASE, __HIP_MEMORY_SCOPE_AGENT);

#pragma unroll 1
  for (int t = 0; t < S_; ++t) {
    // prefetch xp[t] (independent of the handshake)
    u16 xpr[3][4];
#pragma unroll
    for (int g = 0; g < 3; ++g)
#pragma unroll
      for (int rg = 0; rg < 4; ++rg)
        xpr[g][rg] = xp[((long)(b0 + rg) * S_ + t) * TD_ + g * 512 + ch];

    // wait until all 16 cg WGs of this bg published h[t-1]
    if (wave == 0) {
      unsigned tgt = (unsigned)(t + 1);
      bool ok;
      int it = 0;
      do {
        unsigned v = __hip_atomic_load(&bgflags[lane & 15], __ATOMIC_RELAXED,
                                       __HIP_MEMORY_SCOPE_AGENT);
        ok = __all(v >= tgt);
        if (!ok) __builtin_amdgcn_s_sleep(1);
      } while (!ok && ++it < (1 << 20));
      __threadfence();   // acquire: invalidate stale L1/L2 before h reads
    }
    __syncthreads();

    // stage h[t-1] (bg slice, 32x512 bf16) into LDS, XOR-swizzled
    const u16* hsrc = hbuf + ((long)(((t + 1) & 1) * 128 + bg * 32)) * 512;
#pragma unroll
    for (int i = 0; i < 8; ++i) {
      int u = tid + i * 256;
      int row = u >> 6, c8 = u & 63;
      u32x4 v = *(const u32x4*)(hsrc + row * 512 + c8 * 8);
      *(u32x4*)&sH[row * 512 + ((c8 ^ (row & 7)) * 8)] = v;
    }
    __syncthreads();

    // gh = h @ Whh^T for this wave's 3 gate tiles
    f32x4 acc[3] = {};
    int arow = mw * 16 + rr;
    int abase = arow * 512;
    int axor = arow & 7;
#pragma unroll
    for (int ks = 0; ks < 16; ++ks) {
      bf16x8 af = __builtin_bit_cast(
          bf16x8, *(const u32x4*)&sH[abase + (((ks * 4 + kq) ^ axor) * 8)]);
#pragma unroll
      for (int g = 0; g < 3; ++g)
        acc[g] = __builtin_amdgcn_mfma_f32_16x16x32_bf16(
            af, __builtin_bit_cast(bf16x8, wf[g][ks]), acc[g], 0, 0, 0);
    }

    // gates + h update + publish
    u16* hdst = hbuf + (long)((t & 1) * 128) * 512;
#pragma unroll
    for (int rg = 0; rg < 4; ++rg) {
      float xr = bf2f(xpr[0][rg]);
      float xz = bf2f(xpr[1][rg]);
      float xn = bf2f(xpr[2][rg]);
      float hr = acc[0][rg] + bh[0];
      float hz = acc[1][rg] + bh[1];
      float hn = acc[2][rg] + bh[2];
      float r = 1.f / (1.f + __expf(-(xr + hr)));
      float z = 1.f / (1.f + __expf(-(xz + hz)));
      float n = tanhf(xn + r * hn);
      float h2 = (1.f - z) * n + z * mh[rg];
      mh[rg] = h2;
      u16 hb = f2bf(h2);
      hdst[(long)(b0 + rg) * 512 + ch] = hb;
      xout[((long)(b0 + rg) * S_ + t) * D_ + ch] = hb;
    }
    __syncthreads();               // all waves' stores at L2 (vmcnt drain)
    if (tid == 0)                  // release: wbl2 then flag -> coherent point
      __hip_atomic_store(&bgflags[cg], (unsigned)(t + 2), __ATOMIC_RELEASE,
                         __HIP_MEMORY_SCOPE_AGENT);
  }

  // final hidden state (fp32 master)
#pragma unroll
  for (int rg = 0; rg < 4; ++rg)
    hfinal[(long)(b0 + rg) * 512 + ch] = mh[rg];
}

extern "C" void kernel_launch(void* const* d_in, const int* in_sizes, int n_in,
                              void* d_out, int out_size, void* d_ws, size_t ws_size,
                              hipStream_t stream) {
  const int* padded    = (const int*)d_in[0];
  const float* enc     = (const float*)d_in[2];
  const float* hidden  = (const float*)d_in[3];
  const float* embedding = (const float*)d_in[4];
  const float* w_ih    = (const float*)d_in[5];
  const float* w_hh    = (const float*)d_in[6];
  const float* b_ih    = (const float*)d_in[7];
  const float* b_hh    = (const float*)d_in[8];
  const float* attn_w  = (const float*)d_in[9];
  const float* attn_b  = (const float*)d_in[10];
  const float* out_w   = (const float*)d_in[11];
  const float* out_b   = (const float*)d_in[12];

  if (ws_size < 346656768ULL) return;   // ws budget guard

  char* ws = (char*)d_ws;
  u16* W_IH   = (u16*)(ws + 0);             // 3*1536*512 bf16
  u16* W_HH   = (u16*)(ws + 4718592);
  u16* ATTN_W = (u16*)(ws + 9437184);       // 512*1024
  u16* OUT_W  = (u16*)(ws + 10485760);      // 100*512
  unsigned* FLAGS = (unsigned*)(ws + 10588160);  // 3*64 u32 (repurposed HB0 slot)
  u16* HBUF   = (u16*)(ws + 10850304);      // 2*128*512 bf16 (repurposed HB1 slot)
  u16* XA     = (u16*)(ws + 11112448);      // 65536*512 bf16
  u16* XB     = (u16*)(ws + 78221312);
  u16* XP     = (u16*)(ws + 145330176);     // 65536*1536 bf16
  u16* ATTN_BF = XP;                        // aliases (post-GRU)
  u16* ENC_BF  = (u16*)(ws + 145330176 + 67108864);
  u16* ENCT    = ENC_BF;
  u16* AMASK   = (u16*)(ws + 145330176 + 134217728);

  float* out_logits = (float*)d_out;                 // 65536*100
  float* out_h      = out_logits + 6553600;          // 3*128*512
  float* out_attn   = out_h + 196608;                // 128*512*512

  zero_flags<<<1, 256, 0, stream>>>(FLAGS, 3 * NBG * NCG);
  cvt_f32_bf16<<<512, 256, 0, stream>>>(w_ih, W_IH, 2359296 / 4);
  cvt_f32_bf16<<<512, 256, 0, stream>>>(w_hh, W_HH, 2359296 / 4);
  cvt_f32_bf16<<<256, 256, 0, stream>>>(attn_w, ATTN_W, 524288 / 4);
  cvt_f32_bf16<<<64, 256, 0, stream>>>(out_w, OUT_W, 51200 / 4);
  embed_gather<<<2048, 256, 0, stream>>>(padded, embedding, XA);

  for (int l = 0; l < 3; ++l) {
    const u16* xin = (l == 1) ? XB : XA;
    u16* xout = (l == 1) ? XA : XB;
    gemm_xwt<0><<<dim3(12, 512, 1), 256, 0, stream>>>(
        xin, nullptr, W_IH + l * 786432, b_ih + l * 1536, XP, nullptr,
        1536, 512, 512, 0, 0, 0, 1.f, 1536);
    gru_layer<<<64, 256, 0, stream>>>(
        XP, W_HH + l * 786432, b_hh + l * 1536, hidden + l * 65536,
        HBUF, FLAGS + l * 64, xout, out_h + l * 65536);
  }

  // attention
  cvt_f32_bf16<<<2048, 256, 0, stream>>>(enc, ENC_BF, 33554432 / 4);
  gemm_xwt<1><<<dim3(4, 4, 128), 256, 0, stream>>>(
      XB, nullptr, ENC_BF, nullptr, out_attn, nullptr,
      512, 512, 512, 262144, 262144, 262144, 0.044194173824159216f, 512);
  softmax_rows<<<16384, 256, 0, stream>>>(out_attn, ATTN_BF);
  transpose_enc<<<dim3(8, 8, 128), 256, 0, stream>>>(enc, ENCT);
  gemm_xwt<2><<<dim3(4, 4, 128), 256, 0, stream>>>(
      ATTN_BF, nullptr, ENCT, nullptr, XA, nullptr,
      512, 512, 512, 262144, 262144, 262144, 1.f, 512);
  gemm_xwt<3><<<dim3(4, 512, 1), 256, 0, stream>>>(
      XB, XA, ATTN_W, attn_b, AMASK, XB,
      512, 1024, 512, 0, 0, 0, 1.f, 512);
  gemm_xwt<4><<<dim3(1, 512, 1), 256, 0, stream>>>(
      AMASK, nullptr, OUT_W, out_b, d_out, XB,
      100, 512, 512, 0, 0, 0, 1.f, 100);
}

// Round 3
// 6787.616 us; speedup vs baseline: 4.5223x; 1.7080x over previous
//
#include <hip/hip_runtime.h>

// Decoder: emb -> 3-layer GRU -> scaled-dot attention over encoder -> tanh(linear) -> logits
// Round 2: fence-free GRU handshake.
//   - h exchanged as packed bf16-pairs via RELAXED AGENT atomic u32 stores (write-through
//     to the coherence point; no wbl2/inv cache maintenance)
//   - explicit s_waitcnt vmcnt(0) + relaxed atomic flag store for ordering
//   - consumer reads h with inline-asm global_load_dwordx4 sc0 sc1 (L1+L2 bypass)
//   - Whh fragments pinned register-resident via asm identity

typedef unsigned short u16;
typedef __attribute__((ext_vector_type(8))) __bf16 bf16x8;
typedef __attribute__((ext_vector_type(4))) float f32x4;
typedef __attribute__((ext_vector_type(4))) unsigned int u32x4;

#define D_ 512
#define S_ 512
#define SE_ 512
#define B_ 128
#define V_ 100
#define TD_ 1536
#define NBG 4
#define NCG 16

__device__ __forceinline__ float bf2f(u16 v) {
  unsigned u = ((unsigned)v) << 16;
  return __builtin_bit_cast(float, u);
}
__device__ __forceinline__ u16 f2bf(float f) {
  unsigned u = __builtin_bit_cast(unsigned, f);
  u += 0x7FFF + ((u >> 16) & 1);   // RNE
  return (u16)(u >> 16);
}

// ---------------- elementwise converts / copies ----------------
__global__ __launch_bounds__(256) void cvt_f32_bf16(const float* __restrict__ src,
                                                    u16* __restrict__ dst, long n4) {
  long i = (long)blockIdx.x * 256 + threadIdx.x;
  long stride = (long)gridDim.x * 256;
  for (; i < n4; i += stride) {
    float4 v = ((const float4*)src)[i];
    unsigned long long p = (unsigned long long)f2bf(v.x) |
                           ((unsigned long long)f2bf(v.y) << 16) |
                           ((unsigned long long)f2bf(v.z) << 32) |
                           ((unsigned long long)f2bf(v.w) << 48);
    ((unsigned long long*)dst)[i] = p;
  }
}

__global__ __launch_bounds__(256) void zero_flags(unsigned* __restrict__ f, int n) {
  int i = blockIdx.x * 256 + threadIdx.x;
  if (i < n) f[i] = 0;
}

__global__ __launch_bounds__(256) void embed_gather(const int* __restrict__ tok,
                                                    const float* __restrict__ table,
                                                    u16* __restrict__ out) {
  long i = (long)blockIdx.x * 256 + threadIdx.x;
  long stride = (long)gridDim.x * 256;
  const long tot = 65536L * 128;      // (B*S) rows * 128 float4-groups
  for (; i < tot; i += stride) {
    long row = i >> 7;
    int dq = (int)(i & 127);
    int t = tok[row];
    float4 v = ((const float4*)(table + (long)t * D_))[dq];
    unsigned long long p = (unsigned long long)f2bf(v.x) |
                           ((unsigned long long)f2bf(v.y) << 16) |
                           ((unsigned long long)f2bf(v.z) << 32) |
                           ((unsigned long long)f2bf(v.w) << 48);
    ((unsigned long long*)(out + row * D_))[dq] = p;
  }
}

// enc (B,SE,D) f32 -> encT (B,D,SE) bf16
__global__ __launch_bounds__(256) void transpose_enc(const float* __restrict__ enc,
                                                     u16* __restrict__ encT) {
  __shared__ u16 tile[64][72];
  int b = blockIdx.z, d0 = blockIdx.x * 64, se0 = blockIdx.y * 64;
  const float* src = enc + (long)b * SE_ * D_;
  int t = threadIdx.x;
  int r = t >> 2, cq = (t & 3) * 16;
#pragma unroll
  for (int j = 0; j < 4; ++j) {
    float4 v = *(const float4*)(src + (long)(se0 + r) * D_ + d0 + cq + j * 4);
    tile[r][cq + j * 4 + 0] = f2bf(v.x);
    tile[r][cq + j * 4 + 1] = f2bf(v.y);
    tile[r][cq + j * 4 + 2] = f2bf(v.z);
    tile[r][cq + j * 4 + 3] = f2bf(v.w);
  }
  __syncthreads();
  u16* dst = encT + (long)b * D_ * SE_;
  u16 ov[16];
#pragma unroll
  for (int j = 0; j < 16; ++j) ov[j] = tile[cq + j][r];
  *(u32x4*)(dst + (long)(d0 + r) * SE_ + se0 + cq) = *(u32x4*)&ov[0];
  *(u32x4*)(dst + (long)(d0 + r) * SE_ + se0 + cq + 8) = *(u32x4*)&ov[8];
}

// in-place fp32 softmax over 512-wide rows + bf16 copy
__global__ __launch_bounds__(256) void softmax_rows(float* __restrict__ sc,
                                                    u16* __restrict__ abf) {
  long row = (long)blockIdx.x * 4 + (threadIdx.x >> 6);
  int lane = threadIdx.x & 63;
  float* p = sc + row * 512;
  float4 v0 = ((const float4*)p)[lane * 2];
  float4 v1 = ((const float4*)p)[lane * 2 + 1];
  float vals[8] = {v0.x, v0.y, v0.z, v0.w, v1.x, v1.y, v1.z, v1.w};
  float m = vals[0];
#pragma unroll
  for (int j = 1; j < 8; ++j) m = fmaxf(m, vals[j]);
#pragma unroll
  for (int o = 32; o; o >>= 1) m = fmaxf(m, __shfl_xor(m, o, 64));
  float s = 0.f;
#pragma unroll
  for (int j = 0; j < 8; ++j) { vals[j] = __expf(vals[j] - m); s += vals[j]; }
#pragma unroll
  for (int o = 32; o; o >>= 1) s += __shfl_xor(s, o, 64);
  float inv = 1.f / s;
  u16 ob[8];
#pragma unroll
  for (int j = 0; j < 8; ++j) { vals[j] *= inv; ob[j] = f2bf(vals[j]); }
  float4 w0 = {vals[0], vals[1], vals[2], vals[3]};
  float4 w1 = {vals[4], vals[5], vals[6], vals[7]};
  ((float4*)p)[lane * 2] = w0;
  ((float4*)p)[lane * 2 + 1] = w1;
  *(u32x4*)(abf + row * 512 + lane * 8) = *(u32x4*)ob;
}

// ---------------- generic C = A(M,K) @ W(N,K)^T, bf16 in / f32 acc ----------------
template <int MODE>
__global__ __launch_bounds__(256) void gemm_xwt(
    const u16* __restrict__ A1, const u16* __restrict__ A2, const u16* __restrict__ W,
    const float* __restrict__ bias, void* __restrict__ Cout, const u16* __restrict__ maskSrc,
    int N, int K, int K1, long sAb, long sWb, long sCb, float scale, int ldc) {
  __shared__ u16 sA[128][32];
  __shared__ u16 sW_[128][32];
  int bz = blockIdx.z;
  int n0 = blockIdx.x * 128, m0 = blockIdx.y * 128;
  const u16* Ab = A1 + (long)bz * sAb;
  const u16* Wb = W + (long)bz * sWb;
  int t = threadIdx.x, wave = t >> 6, lane = t & 63;
  int wm = (wave >> 1) * 64, wn = (wave & 1) * 64;
  f32x4 acc[4][4] = {};
  for (int kk = 0; kk < K; kk += 32) {
#pragma unroll
    for (int i = 0; i < 2; ++i) {
      int id = t + i * 256;
      int row = id >> 2, c8 = (id & 3) * 8;
      const u16* src;
      if (MODE == 3 && kk >= K1)
        src = A2 + (long)(m0 + row) * (K - K1) + (kk - K1) + c8;
      else
        src = Ab + (long)(m0 + row) * K1 + kk + c8;
      *(u32x4*)&sA[row][c8] = *(const u32x4*)src;
    }
#pragma unroll
    for (int i = 0; i < 2; ++i) {
      int id = t + i * 256;
      int row = id >> 2, c8 = (id & 3) * 8;
      u32x4 v = {0u, 0u, 0u, 0u};
      if (n0 + row < N) v = *(const u32x4*)(Wb + (long)(n0 + row) * K + kk + c8);
      *(u32x4*)&sW_[row][c8] = v;
    }
    __syncthreads();
    int k8 = (lane >> 4) * 8, rr = lane & 15;
    bf16x8 wf[4];
#pragma unroll
    for (int nt = 0; nt < 4; ++nt)
      wf[nt] = __builtin_bit_cast(bf16x8, *(const u32x4*)&sW_[wn + nt * 16 + rr][k8]);
#pragma unroll
    for (int mt = 0; mt < 4; ++mt) {
      bf16x8 af = __builtin_bit_cast(bf16x8, *(const u32x4*)&sA[wm + mt * 16 + rr][k8]);
#pragma unroll
      for (int nt = 0; nt < 4; ++nt)
        acc[mt][nt] = __builtin_amdgcn_mfma_f32_16x16x32_bf16(af, wf[nt], acc[mt][nt], 0, 0, 0);
    }
    __syncthreads();
  }
  int rq = (lane >> 4) * 4, cl = lane & 15;
#pragma unroll
  for (int mt = 0; mt < 4; ++mt) {
#pragma unroll
    for (int nt = 0; nt < 4; ++nt) {
#pragma unroll
      for (int rg = 0; rg < 4; ++rg) {
        int row = m0 + wm + mt * 16 + rq + rg;
        int col = n0 + wn + nt * 16 + cl;
        float v = acc[mt][nt][rg];
        if (MODE == 0) {
          ((u16*)Cout)[(long)row * ldc + col] = f2bf(v + bias[col]);
        } else if (MODE == 1) {
          ((float*)Cout)[(long)bz * sCb + (long)row * ldc + col] = v * scale;
        } else if (MODE == 2) {
          ((u16*)Cout)[(long)bz * sCb + (long)row * ldc + col] = f2bf(v);
        } else if (MODE == 3) {
          float mk = (bf2f(maskSrc[(long)row * D_]) != 0.f) ? 1.f : 0.f;
          ((u16*)Cout)[(long)row * ldc + col] = f2bf(tanhf(v + bias[col]) * mk);
        } else {
          if (col < N) {
            float mk = (bf2f(maskSrc[(long)row * D_]) != 0.f) ? 1.f : 0.f;
            ((float*)Cout)[(long)row * ldc + col] = (v + bias[col]) * mk;
          }
        }
      }
    }
  }
}

// ---------------- persistent GRU layer (fence-free protocol) ----------------
// grid 64 = 4 bg (32 batch rows) x 16 cg (32 h-chans -> 96 Whh rows).
// h exchange: packed bf16-pair u32 relaxed AGENT atomics (write-through to MALL);
// flags: relaxed AGENT atomics after explicit vmcnt drain; consumer reads h with
// sc0 sc1 (L1+L2 bypass) dwordx4 loads. No release/acquire cache maintenance.
__global__ __launch_bounds__(256, 1) void gru_layer(
    const u16* __restrict__ xp,       // [B*S][1536] bf16
    const u16* __restrict__ whh,      // [1536][512] bf16
    const float* __restrict__ bhh,    // [1536] f32
    const float* __restrict__ hidden, // [B][512] f32 (this layer's h0)
    unsigned* __restrict__ hbuf32,    // [2][B][256] u32 (bf16 pairs)
    unsigned* __restrict__ flags,     // [NBG*NCG]
    u16* __restrict__ xout,           // [B][S][512] bf16
    float* __restrict__ hfinal) {     // [B][512] f32
  __shared__ u16 sH[32 * 512];        // swizzled h tile (32 KB)
  int bid = blockIdx.x;
  int bg = bid >> 4;
  int cg = bid & 15;
  int tid = threadIdx.x;
  int wave = tid >> 6, lane = tid & 63;
  int mw = wave >> 1, nh = wave & 1;
  int rr = lane & 15, kq = lane >> 4;
  int cl = lane & 15, rq = lane >> 4;
  int ch = cg * 32 + nh * 16 + cl;                // this thread's h channel
  int b0 = bg * 32 + mw * 16 + rq * 4;            // batch base (rg 0..3)
  unsigned* bgflags = flags + bg * NCG;

  // --- load Whh B-fragments into registers and PIN them (invariant over t) ---
  u32x4 wf[3][16];
#pragma unroll
  for (int g = 0; g < 3; ++g) {
    const u16* wrow = whh + ((long)(g * 512 + cg * 32 + nh * 16 + rr)) * 512 + kq * 8;
#pragma unroll
    for (int ks = 0; ks < 16; ++ks) {
      wf[g][ks] = *(const u32x4*)(wrow + ks * 32);
      asm volatile("" : "+v"(wf[g][ks]));   // force register residency (no remat)
    }
  }
  float bh[3];
#pragma unroll
  for (int g = 0; g < 3; ++g) bh[g] = bhh[g * 512 + ch];

  // --- init fp32 master + publish bf16 h[-1] pairs into buf parity 1 ---
  float mh[4];
  unsigned hb32[4];
#pragma unroll
  for (int rg = 0; rg < 4; ++rg) {
    mh[rg] = hidden[(long)(b0 + rg) * 512 + ch];
    hb32[rg] = (unsigned)f2bf(mh[rg]);
  }
#pragma unroll
  for (int rg = 0; rg < 4; ++rg) {
    unsigned prt = (unsigned)__shfl_xor((int)hb32[rg], 1);
    if (!(cl & 1))
      __hip_atomic_store(&hbuf32[(long)(128 + b0 + rg) * 256 + (ch >> 1)],
                         hb32[rg] | (prt << 16), __ATOMIC_RELAXED,
                         __HIP_MEMORY_SCOPE_AGENT);
  }
  asm volatile("s_waitcnt vmcnt(0)" ::: "memory");
  __syncthreads();
  if (tid == 0)
    __hip_atomic_store(&bgflags[cg], 1u, __ATOMIC_RELAXED, __HIP_MEMORY_SCOPE_AGENT);

#pragma unroll 1
  for (int t = 0; t < S_; ++t) {
    // prefetch xp[t] (independent of the handshake)
    u16 xpr[3][4];
#pragma unroll
    for (int g = 0; g < 3; ++g)
#pragma unroll
      for (int rg = 0; rg < 4; ++rg)
        xpr[g][rg] = xp[((long)(b0 + rg) * S_ + t) * TD_ + g * 512 + ch];

    // all threads poll the 16 cg flags (lane&15 -> flag) until h[t-1] published
    {
      unsigned tgt = (unsigned)(t + 1);
      int it = 0;
      bool ok;
      do {
        unsigned v = __hip_atomic_load(&bgflags[lane & 15], __ATOMIC_RELAXED,
                                       __HIP_MEMORY_SCOPE_AGENT);
        ok = (bool)__all((int)(v >= tgt));
        if (!ok) __builtin_amdgcn_s_sleep(2);
      } while (!ok && ++it < (1 << 22));
    }
    asm volatile("" ::: "memory");

    // stage h[t-1] (bg slice, 32x512 bf16 = 2048 x 16B) via L1+L2-bypass loads
    const unsigned* hsrc = hbuf32 + (long)(((t + 1) & 1) * 128 + bg * 32) * 256;
    u32x4 vv[8];
#pragma unroll
    for (int i = 0; i < 8; ++i) {
      int u = tid + i * 256;
      int row = u >> 6, c8 = u & 63;
      const unsigned* src = hsrc + row * 256 + c8 * 4;
      asm volatile("global_load_dwordx4 %0, %1, off sc0 sc1"
                   : "=&v"(vv[i]) : "v"(src) : "memory");
    }
    asm volatile("s_waitcnt vmcnt(0)" ::: "memory");
    __builtin_amdgcn_sched_barrier(0);
#pragma unroll
    for (int i = 0; i < 8; ++i) {
      int u = tid + i * 256;
      int row = u >> 6, c8 = u & 63;
      *(u32x4*)&sH[row * 512 + ((c8 ^ (row & 7)) * 8)] = vv[i];
    }
    __syncthreads();

    // gh = h @ Whh^T for this wave's 3 gate tiles
    f32x4 acc[3] = {};
    int arow = mw * 16 + rr;
    int abase = arow * 512;
    int axor = arow & 7;
#pragma unroll
    for (int ks = 0; ks < 16; ++ks) {
      bf16x8 af = __builtin_bit_cast(
          bf16x8, *(const u32x4*)&sH[abase + (((ks * 4 + kq) ^ axor) * 8)]);
#pragma unroll
      for (int g = 0; g < 3; ++g)
        acc[g] = __builtin_amdgcn_mfma_f32_16x16x32_bf16(
            af, __builtin_bit_cast(bf16x8, wf[g][ks]), acc[g], 0, 0, 0);
    }

    // gates + h update + publish
#pragma unroll
    for (int rg = 0; rg < 4; ++rg) {
      float xr = bf2f(xpr[0][rg]);
      float xz = bf2f(xpr[1][rg]);
      float xn = bf2f(xpr[2][rg]);
      float hr = acc[0][rg] + bh[0];
      float hz = acc[1][rg] + bh[1];
      float hn = acc[2][rg] + bh[2];
      float r = 1.f / (1.f + __expf(-(xr + hr)));
      float z = 1.f / (1.f + __expf(-(xz + hz)));
      float n = tanhf(xn + r * hn);
      float h2 = (1.f - z) * n + z * mh[rg];
      mh[rg] = h2;
      u16 hb = f2bf(h2);
      hb32[rg] = (unsigned)hb;
      xout[((long)(b0 + rg) * S_ + t) * D_ + ch] = hb;
    }
#pragma unroll
    for (int rg = 0; rg < 4; ++rg) {
      unsigned prt = (unsigned)__shfl_xor((int)hb32[rg], 1);
      if (!(cl & 1))
        __hip_atomic_store(&hbuf32[(long)((t & 1) * 128 + b0 + rg) * 256 + (ch >> 1)],
                           hb32[rg] | (prt << 16), __ATOMIC_RELAXED,
                           __HIP_MEMORY_SCOPE_AGENT);
    }
    asm volatile("s_waitcnt vmcnt(0)" ::: "memory");   // data committed at far point
    __syncthreads();                                   // all waves drained
    if (tid == 0)
      __hip_atomic_store(&bgflags[cg], (unsigned)(t + 2), __ATOMIC_RELAXED,
                         __HIP_MEMORY_SCOPE_AGENT);
  }

  // final hidden state (fp32 master)
#pragma unroll
  for (int rg = 0; rg < 4; ++rg)
    hfinal[(long)(b0 + rg) * 512 + ch] = mh[rg];
}

extern "C" void kernel_launch(void* const* d_in, const int* in_sizes, int n_in,
                              void* d_out, int out_size, void* d_ws, size_t ws_size,
                              hipStream_t stream) {
  const int* padded    = (const int*)d_in[0];
  const float* enc     = (const float*)d_in[2];
  const float* hidden  = (const float*)d_in[3];
  const float* embedding = (const float*)d_in[4];
  const float* w_ih    = (const float*)d_in[5];
  const float* w_hh    = (const float*)d_in[6];
  const float* b_ih    = (const float*)d_in[7];
  const float* b_hh    = (const float*)d_in[8];
  const float* attn_w  = (const float*)d_in[9];
  const float* attn_b  = (const float*)d_in[10];
  const float* out_w   = (const float*)d_in[11];
  const float* out_b   = (const float*)d_in[12];

  if (ws_size < 346656768ULL) return;   // ws budget guard

  char* ws = (char*)d_ws;
  u16* W_IH   = (u16*)(ws + 0);             // 3*1536*512 bf16
  u16* W_HH   = (u16*)(ws + 4718592);
  u16* ATTN_W = (u16*)(ws + 9437184);       // 512*1024
  u16* OUT_W  = (u16*)(ws + 10485760);      // 100*512
  unsigned* FLAGS = (unsigned*)(ws + 10588160);  // 3*64 u32
  unsigned* HBUF32 = (unsigned*)(ws + 10850304); // 2*128*256 u32 = 256 KB
  u16* XA     = (u16*)(ws + 11112448);      // 65536*512 bf16
  u16* XB     = (u16*)(ws + 78221312);
  u16* XP     = (u16*)(ws + 145330176);     // 65536*1536 bf16
  u16* ATTN_BF = XP;                        // aliases (post-GRU)
  u16* ENC_BF  = (u16*)(ws + 145330176 + 67108864);
  u16* ENCT    = ENC_BF;
  u16* AMASK   = (u16*)(ws + 145330176 + 134217728);

  float* out_logits = (float*)d_out;                 // 65536*100
  float* out_h      = out_logits + 6553600;          // 3*128*512
  float* out_attn   = out_h + 196608;                // 128*512*512

  zero_flags<<<1, 256, 0, stream>>>(FLAGS, 3 * NBG * NCG);
  cvt_f32_bf16<<<512, 256, 0, stream>>>(w_ih, W_IH, 2359296 / 4);
  cvt_f32_bf16<<<512, 256, 0, stream>>>(w_hh, W_HH, 2359296 / 4);
  cvt_f32_bf16<<<256, 256, 0, stream>>>(attn_w, ATTN_W, 524288 / 4);
  cvt_f32_bf16<<<64, 256, 0, stream>>>(out_w, OUT_W, 51200 / 4);
  embed_gather<<<2048, 256, 0, stream>>>(padded, embedding, XA);

  for (int l = 0; l < 3; ++l) {
    const u16* xin = (l == 1) ? XB : XA;
    u16* xout = (l == 1) ? XA : XB;
    gemm_xwt<0><<<dim3(12, 512, 1), 256, 0, stream>>>(
        xin, nullptr, W_IH + l * 786432, b_ih + l * 1536, XP, nullptr,
        1536, 512, 512, 0, 0, 0, 1.f, 1536);
    gru_layer<<<64, 256, 0, stream>>>(
        XP, W_HH + l * 786432, b_hh + l * 1536, hidden + l * 65536,
        HBUF32, FLAGS + l * 64, xout, out_h + l * 65536);
  }

  // attention
  cvt_f32_bf16<<<2048, 256, 0, stream>>>(enc, ENC_BF, 33554432 / 4);
  gemm_xwt<1><<<dim3(4, 4, 128), 256, 0, stream>>>(
      XB, nullptr, ENC_BF, nullptr, out_attn, nullptr,
      512, 512, 512, 262144, 262144, 262144, 0.044194173824159216f, 512);
  softmax_rows<<<16384, 256, 0, stream>>>(out_attn, ATTN_BF);
  transpose_enc<<<dim3(8, 8, 128), 256, 0, stream>>>(enc, ENCT);
  gemm_xwt<2><<<dim3(4, 4, 128), 256, 0, stream>>>(
      ATTN_BF, nullptr, ENCT, nullptr, XA, nullptr,
      512, 512, 512, 262144, 262144, 262144, 1.f, 512);
  gemm_xwt<3><<<dim3(4, 512, 1), 256, 0, stream>>>(
      XB, XA, ATTN_W, attn_b, AMASK, XB,
      512, 1024, 512, 0, 0, 0, 1.f, 512);
  gemm_xwt<4><<<dim3(1, 512, 1), 256, 0, stream>>>(
      AMASK, nullptr, OUT_W, out_b, d_out, XB,
      100, 512, 512, 0, 0, 0, 1.f, 100);
}

// Round 4
// 6451.288 us; speedup vs baseline: 4.7581x; 1.0521x over previous
//
#include <hip/hip_runtime.h>

// Decoder: emb -> 3-layer GRU -> scaled-dot attention over encoder -> tanh(linear) -> logits
// Round 3: wavefront-pipelined GRU (all 3 layers concurrent, 514 phases not 1536).
//   - one persistent kernel, 192 WGs x 512 thr: waves 0-3 gh=h@Whh^T, waves 4-7 xp in-loop
//     (l>0: from layer-below h via ring; l==0: from embedding table, staged pre-poll)
//   - h exchange: 3-slot ring of packed bf16 pairs, relaxed AGENT atomics (IC-coherent,
//     no wbl2/inv); flags: own>=t+1, below>=t+2, above>=t-1 (ring WAR-safe)
//   - weights streamed from L2 in two K-chunks/phase (pre-poll + mid-MFMA issue)
//   - flags zeroed via bypass atomic stores; pre-GRU cvt/transpose traffic scrubs L2

typedef unsigned short u16;
typedef __attribute__((ext_vector_type(8))) __bf16 bf16x8;
typedef __attribute__((ext_vector_type(4))) float f32x4;
typedef __attribute__((ext_vector_type(4))) unsigned int u32x4;

#define D_ 512
#define S_ 512
#define SE_ 512
#define B_ 128
#define V_ 100
#define TD_ 1536

__device__ __forceinline__ float bf2f(u16 v) {
  unsigned u = ((unsigned)v) << 16;
  return __builtin_bit_cast(float, u);
}
__device__ __forceinline__ u16 f2bf(float f) {
  unsigned u = __builtin_bit_cast(unsigned, f);
  u += 0x7FFF + ((u >> 16) & 1);   // RNE
  return (u16)(u >> 16);
}

// ---------------- elementwise converts ----------------
__global__ __launch_bounds__(256) void cvt_f32_bf16(const float* __restrict__ src,
                                                    u16* __restrict__ dst, long n4) {
  long i = (long)blockIdx.x * 256 + threadIdx.x;
  long stride = (long)gridDim.x * 256;
  for (; i < n4; i += stride) {
    float4 v = ((const float4*)src)[i];
    unsigned long long p = (unsigned long long)f2bf(v.x) |
                           ((unsigned long long)f2bf(v.y) << 16) |
                           ((unsigned long long)f2bf(v.z) << 32) |
                           ((unsigned long long)f2bf(v.w) << 48);
    ((unsigned long long*)dst)[i] = p;
  }
}

// zero flags at the coherence point (bypass stores - no stale-L2 window)
__global__ __launch_bounds__(256) void zero_flags(unsigned* __restrict__ f, int n) {
  int i = blockIdx.x * 256 + threadIdx.x;
  if (i < n)
    __hip_atomic_store(&f[i], 0u, __ATOMIC_RELAXED, __HIP_MEMORY_SCOPE_AGENT);
}

// enc (B,SE,D) f32 -> encT (B,D,SE) bf16
__global__ __launch_bounds__(256) void transpose_enc(const float* __restrict__ enc,
                                                     u16* __restrict__ encT) {
  __shared__ u16 tile[64][72];
  int b = blockIdx.z, d0 = blockIdx.x * 64, se0 = blockIdx.y * 64;
  const float* src = enc + (long)b * SE_ * D_;
  int t = threadIdx.x;
  int r = t >> 2, cq = (t & 3) * 16;
#pragma unroll
  for (int j = 0; j < 4; ++j) {
    float4 v = *(const float4*)(src + (long)(se0 + r) * D_ + d0 + cq + j * 4);
    tile[r][cq + j * 4 + 0] = f2bf(v.x);
    tile[r][cq + j * 4 + 1] = f2bf(v.y);
    tile[r][cq + j * 4 + 2] = f2bf(v.z);
    tile[r][cq + j * 4 + 3] = f2bf(v.w);
  }
  __syncthreads();
  u16* dst = encT + (long)b * D_ * SE_;
  u16 ov[16];
#pragma unroll
  for (int j = 0; j < 16; ++j) ov[j] = tile[cq + j][r];
  *(u32x4*)(dst + (long)(d0 + r) * SE_ + se0 + cq) = *(u32x4*)&ov[0];
  *(u32x4*)(dst + (long)(d0 + r) * SE_ + se0 + cq + 8) = *(u32x4*)&ov[8];
}

// in-place fp32 softmax over 512-wide rows + bf16 copy
__global__ __launch_bounds__(256) void softmax_rows(float* __restrict__ sc,
                                                    u16* __restrict__ abf) {
  long row = (long)blockIdx.x * 4 + (threadIdx.x >> 6);
  int lane = threadIdx.x & 63;
  float* p = sc + row * 512;
  float4 v0 = ((const float4*)p)[lane * 2];
  float4 v1 = ((const float4*)p)[lane * 2 + 1];
  float vals[8] = {v0.x, v0.y, v0.z, v0.w, v1.x, v1.y, v1.z, v1.w};
  float m = vals[0];
#pragma unroll
  for (int j = 1; j < 8; ++j) m = fmaxf(m, vals[j]);
#pragma unroll
  for (int o = 32; o; o >>= 1) m = fmaxf(m, __shfl_xor(m, o, 64));
  float s = 0.f;
#pragma unroll
  for (int j = 0; j < 8; ++j) { vals[j] = __expf(vals[j] - m); s += vals[j]; }
#pragma unroll
  for (int o = 32; o; o >>= 1) s += __shfl_xor(s, o, 64);
  float inv = 1.f / s;
  u16 ob[8];
#pragma unroll
  for (int j = 0; j < 8; ++j) { vals[j] *= inv; ob[j] = f2bf(vals[j]); }
  float4 w0 = {vals[0], vals[1], vals[2], vals[3]};
  float4 w1 = {vals[4], vals[5], vals[6], vals[7]};
  ((float4*)p)[lane * 2] = w0;
  ((float4*)p)[lane * 2 + 1] = w1;
  *(u32x4*)(abf + row * 512 + lane * 8) = *(u32x4*)ob;
}

// ---------------- generic C = A(M,K) @ W(N,K)^T, bf16 in / f32 acc ----------------
// MODE 1: *scale -> f32 batched (scores; WF32: W is f32, cvt in staging)
// MODE 2: -> bf16 batched (context) MODE 3: split-K A, tanh(+bias)*mask -> bf16
// MODE 4: (+bias)*mask -> f32, col<N (logits)
template <int MODE, int WF32>
__global__ __launch_bounds__(256) void gemm_xwt(
    const u16* __restrict__ A1, const u16* __restrict__ A2, const u16* __restrict__ W,
    const float* __restrict__ bias, void* __restrict__ Cout, const u16* __restrict__ maskSrc,
    int N, int K, int K1, long sAb, long sWb, long sCb, float scale, int ldc) {
  __shared__ u16 sA[128][32];
  __shared__ u16 sW_[128][32];
  int bz = blockIdx.z;
  int n0 = blockIdx.x * 128, m0 = blockIdx.y * 128;
  const u16* Ab = A1 + (long)bz * sAb;
  int t = threadIdx.x, wave = t >> 6, lane = t & 63;
  int wm = (wave >> 1) * 64, wn = (wave & 1) * 64;
  f32x4 acc[4][4] = {};
  for (int kk = 0; kk < K; kk += 32) {
#pragma unroll
    for (int i = 0; i < 2; ++i) {
      int id = t + i * 256;
      int row = id >> 2, c8 = (id & 3) * 8;
      const u16* src;
      if (MODE == 3 && kk >= K1)
        src = A2 + (long)(m0 + row) * (K - K1) + (kk - K1) + c8;
      else
        src = Ab + (long)(m0 + row) * K1 + kk + c8;
      *(u32x4*)&sA[row][c8] = *(const u32x4*)src;
    }
#pragma unroll
    for (int i = 0; i < 2; ++i) {
      int id = t + i * 256;
      int row = id >> 2, c8 = (id & 3) * 8;
      if (WF32) {
        const float* wsrc = ((const float*)W) + (long)bz * sWb + (long)(n0 + row) * K + kk + c8;
        float4 va = *(const float4*)wsrc;
        float4 vb = *(const float4*)(wsrc + 4);
        u16 tmp[8] = {f2bf(va.x), f2bf(va.y), f2bf(va.z), f2bf(va.w),
                      f2bf(vb.x), f2bf(vb.y), f2bf(vb.z), f2bf(vb.w)};
        *(u32x4*)&sW_[row][c8] = *(u32x4*)tmp;
      } else {
        u32x4 v = {0u, 0u, 0u, 0u};
        if (n0 + row < N) v = *(const u32x4*)(W + (long)bz * sWb + (long)(n0 + row) * K + kk + c8);
        *(u32x4*)&sW_[row][c8] = v;
      }
    }
    __syncthreads();
    int k8 = (lane >> 4) * 8, rr = lane & 15;
    bf16x8 wf[4];
#pragma unroll
    for (int nt = 0; nt < 4; ++nt)
      wf[nt] = __builtin_bit_cast(bf16x8, *(const u32x4*)&sW_[wn + nt * 16 + rr][k8]);
#pragma unroll
    for (int mt = 0; mt < 4; ++mt) {
      bf16x8 af = __builtin_bit_cast(bf16x8, *(const u32x4*)&sA[wm + mt * 16 + rr][k8]);
#pragma unroll
      for (int nt = 0; nt < 4; ++nt)
        acc[mt][nt] = __builtin_amdgcn_mfma_f32_16x16x32_bf16(af, wf[nt], acc[mt][nt], 0, 0, 0);
    }
    __syncthreads();
  }
  int rq = (lane >> 4) * 4, cl = lane & 15;
#pragma unroll
  for (int mt = 0; mt < 4; ++mt) {
#pragma unroll
    for (int nt = 0; nt < 4; ++nt) {
#pragma unroll
      for (int rg = 0; rg < 4; ++rg) {
        int row = m0 + wm + mt * 16 + rq + rg;
        int col = n0 + wn + nt * 16 + cl;
        float v = acc[mt][nt][rg];
        if (MODE == 1) {
          ((float*)Cout)[(long)bz * sCb + (long)row * ldc + col] = v * scale;
        } else if (MODE == 2) {
          ((u16*)Cout)[(long)bz * sCb + (long)row * ldc + col] = f2bf(v);
        } else if (MODE == 3) {
          float mk = (bf2f(maskSrc[(long)row * D_]) != 0.f) ? 1.f : 0.f;
          ((u16*)Cout)[(long)row * ldc + col] = f2bf(tanhf(v + bias[col]) * mk);
        } else {
          if (col < N) {
            float mk = (bf2f(maskSrc[(long)row * D_]) != 0.f) ? 1.f : 0.f;
            ((float*)Cout)[(long)row * ldc + col] = (v + bias[col]) * mk;
          }
        }
      }
    }
  }
}

// ---------------- wavefront-pipelined 3-layer GRU ----------------
// grid 192 = l(3) x bg(4) x cg(16); 512 threads: waves 0-3 gh, waves 4-7 xp.
// ring[l]: 3 slots x [128][256] u32 (packed bf16 pairs), IC-coherent bypass ops.
// flags[l][bg][cg]: t+2 after step t. Poll: own>=t+1; below>=t+2 (xp,l>0);
// above>=t-1 (gh,l<2; ring WAR back-pressure).
__global__ __launch_bounds__(512, 1) void gru_wave(
    const int* __restrict__ tok, const float* __restrict__ embedding,
    const u16* __restrict__ wih_all, const u16* __restrict__ whh_all,
    const float* __restrict__ bih_all, const float* __restrict__ bhh_all,
    const float* __restrict__ hidden,
    unsigned* __restrict__ ring, unsigned* __restrict__ flags,
    u16* __restrict__ xout2, float* __restrict__ hfin) {
  __shared__ u16 sHA[32 * 512];
  __shared__ u16 sHB[32 * 512];
  __shared__ float sXP[32 * 100];
  const int bid = blockIdx.x;
  const int l = bid >> 6;
  const int bg = (bid >> 4) & 3;
  const int cg = bid & 15;
  const int tid = threadIdx.x;
  const int wave = tid >> 6;
  const bool isXp = wave >= 4;
  const int wv = wave & 3;
  const int lane = tid & 63;
  const int mw = wv >> 1, nh = wv & 1;
  const int rr = lane & 15, kq = lane >> 4;
  const int cl = lane & 15, rq = lane >> 4;
  const int chL = nh * 16 + cl;
  const int ch = cg * 32 + chL;
  const int bL = mw * 16 + rq * 4;
  const int b0 = bg * 32 + bL;
  unsigned* myflags = flags + l * 64 + bg * 16;
  const u16* Wsrc = (isXp ? wih_all : whh_all) + (long)l * 786432;
  const float* bsrc = (isXp ? bih_all : bhh_all) + l * 1536;
  const u16* wrow[3];
  float bh[3];
#pragma unroll
  for (int g = 0; g < 3; ++g) {
    wrow[g] = Wsrc + ((long)(g * 512 + cg * 32 + nh * 16 + rr)) * 512 + kq * 8;
    bh[g] = bsrc[g * 512 + ch];
  }
  unsigned* ringL = ring + l * 3 * 32768;
  const unsigned* ringB = ring + (l - 1) * 3 * 32768;   // valid for l>0

  // --- init: fp32 master + publish h[-1] into slot 2 ---
  float mh[4] = {0.f, 0.f, 0.f, 0.f};
  if (!isXp) {
    unsigned pk[4];
#pragma unroll
    for (int rg = 0; rg < 4; ++rg) {
      mh[rg] = hidden[(long)l * 65536 + (long)(b0 + rg) * 512 + ch];
      pk[rg] = (unsigned)f2bf(mh[rg]);
    }
#pragma unroll
    for (int rg = 0; rg < 4; ++rg) {
      unsigned prt = (unsigned)__shfl_xor((int)pk[rg], 1);
      if (!(cl & 1))
        __hip_atomic_store(&ringL[2 * 32768 + (b0 + rg) * 256 + (ch >> 1)],
                           pk[rg] | (prt << 16), __ATOMIC_RELAXED,
                           __HIP_MEMORY_SCOPE_AGENT);
    }
  }
  asm volatile("s_waitcnt vmcnt(0)" ::: "memory");
  __syncthreads();
  if (tid == 0)
    __hip_atomic_store(&myflags[cg], 1u, __ATOMIC_RELAXED, __HIP_MEMORY_SCOPE_AGENT);

  int sl = 0;   // t % 3
#pragma unroll 1
  for (int t = 0; t < S_; ++t) {
    const int slp = (sl == 0) ? 2 : sl - 1;   // (t-1) % 3
    // --- issue weight chunk A (K 0..255), off critical path ---
    u32x4 wf[3][8];
#pragma unroll
    for (int g = 0; g < 3; ++g)
#pragma unroll
      for (int j = 0; j < 8; ++j)
        wf[g][j] = *(const u32x4*)(wrow[g] + j * 32);
    // --- layer-0 xp: stage embedding rows into sHB (flag-independent) ---
    if (isXp && l == 0) {
      int u = tid - 256;
#pragma unroll
      for (int i = 0; i < 2; ++i) {
        int row = (u >> 4) + i * 16;
        int c0 = (u & 15) * 32;
        int tk = tok[(long)(bg * 32 + row) * 512 + t];
        const float* es = embedding + (long)tk * 512 + c0;
        u16 tmp[32];
#pragma unroll
        for (int q = 0; q < 8; ++q) {
          float4 v = *(const float4*)(es + q * 4);
          tmp[q * 4 + 0] = f2bf(v.x); tmp[q * 4 + 1] = f2bf(v.y);
          tmp[q * 4 + 2] = f2bf(v.z); tmp[q * 4 + 3] = f2bf(v.w);
        }
#pragma unroll
        for (int q = 0; q < 4; ++q) {
          int grp = (c0 >> 3) + q;
          *(u32x4*)&sHB[row * 512 + ((grp ^ (row & 7)) * 8)] = *(u32x4*)&tmp[q * 8];
        }
      }
    }
    asm volatile("" ::: "memory");
    // --- poll (per-wave minimal conditions) ---
    if (!(isXp && l == 0)) {
      const unsigned* fb;
      int tgt;
      if (isXp) { fb = flags + (l - 1) * 64 + bg * 16; tgt = t + 2; }
      else if (lane >= 32 && l < 2) { fb = flags + (l + 1) * 64 + bg * 16; tgt = t - 1; }
      else { fb = myflags; tgt = t + 1; }
      const unsigned* fp = fb + (lane & 15);
      int it = 0;
      bool ok;
      do {
        unsigned v = __hip_atomic_load(fp, __ATOMIC_RELAXED, __HIP_MEMORY_SCOPE_AGENT);
        ok = (bool)__all((int)v >= tgt);
        if (!ok) __builtin_amdgcn_s_sleep(2);
      } while (!ok && ++it < (1 << 22));
    }
    asm volatile("" ::: "memory");
    // --- stage h slices (bypass loads from ring) ---
    if (!isXp || l > 0) {
      const unsigned* hsrc = (!isXp ? (const unsigned*)ringL + slp * 32768
                                    : ringB + sl * 32768) + bg * 32 * 256;
      u16* dstL = !isXp ? sHA : sHB;
      int u = isXp ? tid - 256 : tid;
      u32x4 vv[8];
#pragma unroll
      for (int i = 0; i < 8; ++i) {
        int uu = u + i * 256;
        const unsigned* src = hsrc + (uu >> 6) * 256 + (uu & 63) * 4;
        asm volatile("global_load_dwordx4 %0, %1, off sc0 sc1"
                     : "=&v"(vv[i]) : "v"(src) : "memory");
      }
      asm volatile("s_waitcnt vmcnt(0)" ::: "memory");
      __builtin_amdgcn_sched_barrier(0);
#pragma unroll
      for (int i = 0; i < 8; ++i) {
        int uu = u + i * 256;
        int row = uu >> 6, c8 = uu & 63;
        *(u32x4*)&dstL[row * 512 + ((c8 ^ (row & 7)) * 8)] = vv[i];
      }
    }
    __syncthreads();
    // --- MFMA: chunk A, reload chunk B, chunk B ---
    f32x4 acc[3] = {};
    const u16* sH = isXp ? sHB : sHA;
    const int abase = (mw * 16 + rr) * 512;
    const int axor = (mw * 16 + rr) & 7;
#pragma unroll
    for (int j = 0; j < 8; ++j) {
      bf16x8 af = __builtin_bit_cast(
          bf16x8, *(const u32x4*)&sH[abase + (((j * 4 + kq) ^ axor) * 8)]);
#pragma unroll
      for (int g = 0; g < 3; ++g)
        acc[g] = __builtin_amdgcn_mfma_f32_16x16x32_bf16(
            af, __builtin_bit_cast(bf16x8, wf[g][j]), acc[g], 0, 0, 0);
    }
#pragma unroll
    for (int g = 0; g < 3; ++g)
#pragma unroll
      for (int j = 0; j < 8; ++j)
        wf[g][j] = *(const u32x4*)(wrow[g] + (8 + j) * 32);
#pragma unroll
    for (int j = 0; j < 8; ++j) {
      bf16x8 af = __builtin_bit_cast(
          bf16x8, *(const u32x4*)&sH[abase + ((((8 + j) * 4 + kq) ^ axor) * 8)]);
#pragma unroll
      for (int g = 0; g < 3; ++g)
        acc[g] = __builtin_amdgcn_mfma_f32_16x16x32_bf16(
            af, __builtin_bit_cast(bf16x8, wf[g][j]), acc[g], 0, 0, 0);
    }
    if (isXp) {
#pragma unroll
      for (int g = 0; g < 3; ++g)
#pragma unroll
        for (int rg = 0; rg < 4; ++rg)
          sXP[(bL + rg) * 100 + g * 32 + chL] = acc[g][rg] + bh[g];
    }
    __syncthreads();
    // --- gates + publish (gh waves) ---
    if (!isXp) {
      unsigned pk[4];
#pragma unroll
      for (int rg = 0; rg < 4; ++rg) {
        float xr = sXP[(bL + rg) * 100 + chL];
        float xz = sXP[(bL + rg) * 100 + 32 + chL];
        float xn = sXP[(bL + rg) * 100 + 64 + chL];
        float r = 1.f / (1.f + __expf(-(xr + acc[0][rg] + bh[0])));
        float z = 1.f / (1.f + __expf(-(xz + acc[1][rg] + bh[1])));
        float n = tanhf(xn + r * (acc[2][rg] + bh[2]));
        float h2 = (1.f - z) * n + z * mh[rg];
        mh[rg] = h2;
        u16 hb = f2bf(h2);
        pk[rg] = (unsigned)hb;
        if (l == 2) xout2[((long)(b0 + rg) * 512 + t) * 512 + ch] = hb;
      }
#pragma unroll
      for (int rg = 0; rg < 4; ++rg) {
        unsigned prt = (unsigned)__shfl_xor((int)pk[rg], 1);
        if (!(cl & 1))
          __hip_atomic_store(&ringL[sl * 32768 + (b0 + rg) * 256 + (ch >> 1)],
                             pk[rg] | (prt << 16), __ATOMIC_RELAXED,
                             __HIP_MEMORY_SCOPE_AGENT);
      }
      asm volatile("s_waitcnt vmcnt(0)" ::: "memory");
    }
    __syncthreads();
    if (tid == 0)
      __hip_atomic_store(&myflags[cg], (unsigned)(t + 2), __ATOMIC_RELAXED,
                         __HIP_MEMORY_SCOPE_AGENT);
    sl = (sl == 2) ? 0 : sl + 1;
  }
  if (!isXp) {
#pragma unroll
    for (int rg = 0; rg < 4; ++rg)
      hfin[(long)l * 65536 + (long)(b0 + rg) * 512 + ch] = mh[rg];
  }
}

extern "C" void kernel_launch(void* const* d_in, const int* in_sizes, int n_in,
                              void* d_out, int out_size, void* d_ws, size_t ws_size,
                              hipStream_t stream) {
  const int* padded    = (const int*)d_in[0];
  const float* enc     = (const float*)d_in[2];
  const float* hidden  = (const float*)d_in[3];
  const float* embedding = (const float*)d_in[4];
  const float* w_ih    = (const float*)d_in[5];
  const float* w_hh    = (const float*)d_in[6];
  const float* b_ih    = (const float*)d_in[7];
  const float* b_hh    = (const float*)d_in[8];
  const float* attn_w  = (const float*)d_in[9];
  const float* attn_b  = (const float*)d_in[10];
  const float* out_w   = (const float*)d_in[11];
  const float* out_b   = (const float*)d_in[12];

  if (ws_size < 280204288ULL) return;   // ws budget guard

  char* ws = (char*)d_ws;
  u16* W_IH   = (u16*)(ws + 0);               // 3*1536*512 bf16
  u16* W_HH   = (u16*)(ws + 4718592);
  u16* ATTN_W = (u16*)(ws + 9437184);         // 512*1024 bf16
  u16* OUT_W  = (u16*)(ws + 10485760);        // 100*512 bf16
  unsigned* FLAGS = (unsigned*)(ws + 10588160);   // 3*64 u32 (1 KB slot)
  unsigned* RING  = (unsigned*)(ws + 10589184);   // 3*3*128*256 u32 = 1.125 MB
  u16* XA     = (u16*)(ws + 11768832);        // context bf16, 64 MB
  u16* XB     = (u16*)(ws + 78877696);        // dec = layer-2 output, 64 MB
  u16* ENCT   = (u16*)(ws + 145986560);       // enc^T bf16, 64 MB
  u16* AMASK  = (u16*)(ws + 213095424);       // tanh-masked / softmax-bf16 alias, 64 MB
  u16* ATTN_BF = AMASK;

  float* out_logits = (float*)d_out;                 // 65536*100
  float* out_h      = out_logits + 6553600;          // 3*128*512
  float* out_attn   = out_h + 196608;                // 128*512*512

  zero_flags<<<1, 256, 0, stream>>>(FLAGS, 192);
  cvt_f32_bf16<<<512, 256, 0, stream>>>(w_ih, W_IH, 2359296 / 4);
  cvt_f32_bf16<<<512, 256, 0, stream>>>(w_hh, W_HH, 2359296 / 4);
  cvt_f32_bf16<<<256, 256, 0, stream>>>(attn_w, ATTN_W, 524288 / 4);
  cvt_f32_bf16<<<64, 256, 0, stream>>>(out_w, OUT_W, 51200 / 4);
  // pre-GRU: also provides the L2 scrub traffic before ring bypass ops
  transpose_enc<<<dim3(8, 8, 128), 256, 0, stream>>>(enc, ENCT);

  gru_wave<<<192, 512, 0, stream>>>(
      padded, embedding, W_IH, W_HH, b_ih, b_hh, hidden,
      RING, FLAGS, XB, out_h);

  // attention (scores GEMM converts f32 enc in staging; no ENC_BF buffer)
  gemm_xwt<1, 1><<<dim3(4, 4, 128), 256, 0, stream>>>(
      XB, nullptr, (const u16*)enc, nullptr, out_attn, nullptr,
      512, 512, 512, 262144, 262144, 262144, 0.044194173824159216f, 512);
  softmax_rows<<<16384, 256, 0, stream>>>(out_attn, ATTN_BF);
  gemm_xwt<2, 0><<<dim3(4, 4, 128), 256, 0, stream>>>(
      ATTN_BF, nullptr, ENCT, nullptr, XA, nullptr,
      512, 512, 512, 262144, 262144, 262144, 1.f, 512);
  gemm_xwt<3, 0><<<dim3(4, 512, 1), 256, 0, stream>>>(
      XB, XA, ATTN_W, attn_b, AMASK, XB,
      512, 1024, 512, 0, 0, 0, 1.f, 512);
  gemm_xwt<4, 0><<<dim3(1, 512, 1), 256, 0, stream>>>(
      AMASK, nullptr, OUT_W, out_b, d_out, XB,
      100, 512, 512, 0, 0, 0, 1.f, 100);
}

// Round 5
// 5436.319 us; speedup vs baseline: 5.6465x; 1.1867x over previous
//
#include <hip/hip_runtime.h>

// Decoder: emb -> 3-layer GRU -> scaled-dot attention over encoder -> tanh(linear) -> logits
// Round 4: wavefront pipeline (r3) + register-resident weights (r2's wf[3][16], asm-pinned).
//   r3 regression root-caused: per-phase weight restream = 74 MB/phase L2 + HBM thrash
//   (FETCH 803 MB). Weights now loaded once pre-loop; launch_bounds(512,2) caps 256 regs.

typedef unsigned short u16;
typedef __attribute__((ext_vector_type(8))) __bf16 bf16x8;
typedef __attribute__((ext_vector_type(4))) float f32x4;
typedef __attribute__((ext_vector_type(4))) unsigned int u32x4;

#define D_ 512
#define S_ 512
#define SE_ 512
#define B_ 128
#define V_ 100
#define TD_ 1536

__device__ __forceinline__ float bf2f(u16 v) {
  unsigned u = ((unsigned)v) << 16;
  return __builtin_bit_cast(float, u);
}
__device__ __forceinline__ u16 f2bf(float f) {
  unsigned u = __builtin_bit_cast(unsigned, f);
  u += 0x7FFF + ((u >> 16) & 1);   // RNE
  return (u16)(u >> 16);
}

// ---------------- elementwise converts ----------------
__global__ __launch_bounds__(256) void cvt_f32_bf16(const float* __restrict__ src,
                                                    u16* __restrict__ dst, long n4) {
  long i = (long)blockIdx.x * 256 + threadIdx.x;
  long stride = (long)gridDim.x * 256;
  for (; i < n4; i += stride) {
    float4 v = ((const float4*)src)[i];
    unsigned long long p = (unsigned long long)f2bf(v.x) |
                           ((unsigned long long)f2bf(v.y) << 16) |
                           ((unsigned long long)f2bf(v.z) << 32) |
                           ((unsigned long long)f2bf(v.w) << 48);
    ((unsigned long long*)dst)[i] = p;
  }
}

// zero flags at the coherence point (bypass stores - no stale-L2 window)
__global__ __launch_bounds__(256) void zero_flags(unsigned* __restrict__ f, int n) {
  int i = blockIdx.x * 256 + threadIdx.x;
  if (i < n)
    __hip_atomic_store(&f[i], 0u, __ATOMIC_RELAXED, __HIP_MEMORY_SCOPE_AGENT);
}

// enc (B,SE,D) f32 -> encT (B,D,SE) bf16
__global__ __launch_bounds__(256) void transpose_enc(const float* __restrict__ enc,
                                                     u16* __restrict__ encT) {
  __shared__ u16 tile[64][72];
  int b = blockIdx.z, d0 = blockIdx.x * 64, se0 = blockIdx.y * 64;
  const float* src = enc + (long)b * SE_ * D_;
  int t = threadIdx.x;
  int r = t >> 2, cq = (t & 3) * 16;
#pragma unroll
  for (int j = 0; j < 4; ++j) {
    float4 v = *(const float4*)(src + (long)(se0 + r) * D_ + d0 + cq + j * 4);
    tile[r][cq + j * 4 + 0] = f2bf(v.x);
    tile[r][cq + j * 4 + 1] = f2bf(v.y);
    tile[r][cq + j * 4 + 2] = f2bf(v.z);
    tile[r][cq + j * 4 + 3] = f2bf(v.w);
  }
  __syncthreads();
  u16* dst = encT + (long)b * D_ * SE_;
  u16 ov[16];
#pragma unroll
  for (int j = 0; j < 16; ++j) ov[j] = tile[cq + j][r];
  *(u32x4*)(dst + (long)(d0 + r) * SE_ + se0 + cq) = *(u32x4*)&ov[0];
  *(u32x4*)(dst + (long)(d0 + r) * SE_ + se0 + cq + 8) = *(u32x4*)&ov[8];
}

// in-place fp32 softmax over 512-wide rows + bf16 copy
__global__ __launch_bounds__(256) void softmax_rows(float* __restrict__ sc,
                                                    u16* __restrict__ abf) {
  long row = (long)blockIdx.x * 4 + (threadIdx.x >> 6);
  int lane = threadIdx.x & 63;
  float* p = sc + row * 512;
  float4 v0 = ((const float4*)p)[lane * 2];
  float4 v1 = ((const float4*)p)[lane * 2 + 1];
  float vals[8] = {v0.x, v0.y, v0.z, v0.w, v1.x, v1.y, v1.z, v1.w};
  float m = vals[0];
#pragma unroll
  for (int j = 1; j < 8; ++j) m = fmaxf(m, vals[j]);
#pragma unroll
  for (int o = 32; o; o >>= 1) m = fmaxf(m, __shfl_xor(m, o, 64));
  float s = 0.f;
#pragma unroll
  for (int j = 0; j < 8; ++j) { vals[j] = __expf(vals[j] - m); s += vals[j]; }
#pragma unroll
  for (int o = 32; o; o >>= 1) s += __shfl_xor(s, o, 64);
  float inv = 1.f / s;
  u16 ob[8];
#pragma unroll
  for (int j = 0; j < 8; ++j) { vals[j] *= inv; ob[j] = f2bf(vals[j]); }
  float4 w0 = {vals[0], vals[1], vals[2], vals[3]};
  float4 w1 = {vals[4], vals[5], vals[6], vals[7]};
  ((float4*)p)[lane * 2] = w0;
  ((float4*)p)[lane * 2 + 1] = w1;
  *(u32x4*)(abf + row * 512 + lane * 8) = *(u32x4*)ob;
}

// ---------------- generic C = A(M,K) @ W(N,K)^T, bf16 in / f32 acc ----------------
// MODE 1: *scale -> f32 batched (scores; WF32: W is f32, cvt in staging)
// MODE 2: -> bf16 batched (context) MODE 3: split-K A, tanh(+bias)*mask -> bf16
// MODE 4: (+bias)*mask -> f32, col<N (logits)
template <int MODE, int WF32>
__global__ __launch_bounds__(256) void gemm_xwt(
    const u16* __restrict__ A1, const u16* __restrict__ A2, const u16* __restrict__ W,
    const float* __restrict__ bias, void* __restrict__ Cout, const u16* __restrict__ maskSrc,
    int N, int K, int K1, long sAb, long sWb, long sCb, float scale, int ldc) {
  __shared__ u16 sA[128][32];
  __shared__ u16 sW_[128][32];
  int bz = blockIdx.z;
  int n0 = blockIdx.x * 128, m0 = blockIdx.y * 128;
  const u16* Ab = A1 + (long)bz * sAb;
  int t = threadIdx.x, wave = t >> 6, lane = t & 63;
  int wm = (wave >> 1) * 64, wn = (wave & 1) * 64;
  f32x4 acc[4][4] = {};
  for (int kk = 0; kk < K; kk += 32) {
#pragma unroll
    for (int i = 0; i < 2; ++i) {
      int id = t + i * 256;
      int row = id >> 2, c8 = (id & 3) * 8;
      const u16* src;
      if (MODE == 3 && kk >= K1)
        src = A2 + (long)(m0 + row) * (K - K1) + (kk - K1) + c8;
      else
        src = Ab + (long)(m0 + row) * K1 + kk + c8;
      *(u32x4*)&sA[row][c8] = *(const u32x4*)src;
    }
#pragma unroll
    for (int i = 0; i < 2; ++i) {
      int id = t + i * 256;
      int row = id >> 2, c8 = (id & 3) * 8;
      if (WF32) {
        const float* wsrc = ((const float*)W) + (long)bz * sWb + (long)(n0 + row) * K + kk + c8;
        float4 va = *(const float4*)wsrc;
        float4 vb = *(const float4*)(wsrc + 4);
        u16 tmp[8] = {f2bf(va.x), f2bf(va.y), f2bf(va.z), f2bf(va.w),
                      f2bf(vb.x), f2bf(vb.y), f2bf(vb.z), f2bf(vb.w)};
        *(u32x4*)&sW_[row][c8] = *(u32x4*)tmp;
      } else {
        u32x4 v = {0u, 0u, 0u, 0u};
        if (n0 + row < N) v = *(const u32x4*)(W + (long)bz * sWb + (long)(n0 + row) * K + kk + c8);
        *(u32x4*)&sW_[row][c8] = v;
      }
    }
    __syncthreads();
    int k8 = (lane >> 4) * 8, rr = lane & 15;
    bf16x8 wf[4];
#pragma unroll
    for (int nt = 0; nt < 4; ++nt)
      wf[nt] = __builtin_bit_cast(bf16x8, *(const u32x4*)&sW_[wn + nt * 16 + rr][k8]);
#pragma unroll
    for (int mt = 0; mt < 4; ++mt) {
      bf16x8 af = __builtin_bit_cast(bf16x8, *(const u32x4*)&sA[wm + mt * 16 + rr][k8]);
#pragma unroll
      for (int nt = 0; nt < 4; ++nt)
        acc[mt][nt] = __builtin_amdgcn_mfma_f32_16x16x32_bf16(af, wf[nt], acc[mt][nt], 0, 0, 0);
    }
    __syncthreads();
  }
  int rq = (lane >> 4) * 4, cl = lane & 15;
#pragma unroll
  for (int mt = 0; mt < 4; ++mt) {
#pragma unroll
    for (int nt = 0; nt < 4; ++nt) {
#pragma unroll
      for (int rg = 0; rg < 4; ++rg) {
        int row = m0 + wm + mt * 16 + rq + rg;
        int col = n0 + wn + nt * 16 + cl;
        float v = acc[mt][nt][rg];
        if (MODE == 1) {
          ((float*)Cout)[(long)bz * sCb + (long)row * ldc + col] = v * scale;
        } else if (MODE == 2) {
          ((u16*)Cout)[(long)bz * sCb + (long)row * ldc + col] = f2bf(v);
        } else if (MODE == 3) {
          float mk = (bf2f(maskSrc[(long)row * D_]) != 0.f) ? 1.f : 0.f;
          ((u16*)Cout)[(long)row * ldc + col] = f2bf(tanhf(v + bias[col]) * mk);
        } else {
          if (col < N) {
            float mk = (bf2f(maskSrc[(long)row * D_]) != 0.f) ? 1.f : 0.f;
            ((float*)Cout)[(long)row * ldc + col] = (v + bias[col]) * mk;
          }
        }
      }
    }
  }
}

// ---------------- wavefront-pipelined 3-layer GRU ----------------
// grid 192 = l(3) x bg(4) x cg(16); 512 threads: waves 0-3 gh, waves 4-7 xp.
// Weights REGISTER-RESIDENT (wf[3][16], 192 VGPRs/thread, loaded once pre-loop).
// ring[l]: 3 slots x [128][256] u32 (packed bf16 pairs), IC-coherent bypass ops.
// flags[l][bg][cg]: t+2 after step t. Poll: own>=t+1; below>=t+2 (xp,l>0);
// above>=t-1 (gh lanes>=32, l<2; ring WAR back-pressure).
__global__ __launch_bounds__(512, 2) void gru_wave(
    const int* __restrict__ tok, const float* __restrict__ embedding,
    const u16* __restrict__ wih_all, const u16* __restrict__ whh_all,
    const float* __restrict__ bih_all, const float* __restrict__ bhh_all,
    const float* __restrict__ hidden,
    unsigned* __restrict__ ring, unsigned* __restrict__ flags,
    u16* __restrict__ xout2, float* __restrict__ hfin) {
  __shared__ u16 sHA[32 * 512];
  __shared__ u16 sHB[32 * 512];
  __shared__ float sXP[32 * 101];
  const int bid = blockIdx.x;
  const int l = bid >> 6;
  const int bg = (bid >> 4) & 3;
  const int cg = bid & 15;
  const int tid = threadIdx.x;
  const int wave = tid >> 6;
  const bool isXp = wave >= 4;
  const int wv = wave & 3;
  const int lane = tid & 63;
  const int mw = wv >> 1, nh = wv & 1;
  const int rr = lane & 15, kq = lane >> 4;
  const int cl = lane & 15, rq = lane >> 4;
  const int chL = nh * 16 + cl;
  const int ch = cg * 32 + chL;
  const int bL = mw * 16 + rq * 4;
  const int b0 = bg * 32 + bL;
  unsigned* myflags = flags + l * 64 + bg * 16;
  const u16* Wsrc = (isXp ? wih_all : whh_all) + (long)l * 786432;
  const float* bsrc = (isXp ? bih_all : bhh_all) + l * 1536;
  float bh[3];
#pragma unroll
  for (int g = 0; g < 3; ++g) bh[g] = bsrc[g * 512 + ch];
  unsigned* ringL = ring + l * 3 * 32768;
  const unsigned* ringB = ring + (l - 1) * 3 * 32768;   // valid for l>0

  // --- load weight B-fragments into registers ONCE and pin (192 VGPRs) ---
  u32x4 wf[3][16];
#pragma unroll
  for (int g = 0; g < 3; ++g) {
    const u16* wrow = Wsrc + ((long)(g * 512 + cg * 32 + nh * 16 + rr)) * 512 + kq * 8;
#pragma unroll
    for (int ks = 0; ks < 16; ++ks) {
      wf[g][ks] = *(const u32x4*)(wrow + ks * 32);
      asm volatile("" : "+v"(wf[g][ks]));   // force materialization (no remat/reload)
    }
  }

  // --- init: fp32 master + publish h[-1] into slot 2 ---
  float mh[4] = {0.f, 0.f, 0.f, 0.f};
  if (!isXp) {
    unsigned pk[4];
#pragma unroll
    for (int rg = 0; rg < 4; ++rg) {
      mh[rg] = hidden[(long)l * 65536 + (long)(b0 + rg) * 512 + ch];
      pk[rg] = (unsigned)f2bf(mh[rg]);
    }
#pragma unroll
    for (int rg = 0; rg < 4; ++rg) {
      unsigned prt = (unsigned)__shfl_xor((int)pk[rg], 1);
      if (!(cl & 1))
        __hip_atomic_store(&ringL[2 * 32768 + (b0 + rg) * 256 + (ch >> 1)],
                           pk[rg] | (prt << 16), __ATOMIC_RELAXED,
                           __HIP_MEMORY_SCOPE_AGENT);
    }
  }
  asm volatile("s_waitcnt vmcnt(0)" ::: "memory");
  __syncthreads();
  if (tid == 0)
    __hip_atomic_store(&myflags[cg], 1u, __ATOMIC_RELAXED, __HIP_MEMORY_SCOPE_AGENT);

  int sl = 0;   // t % 3
#pragma unroll 1
  for (int t = 0; t < S_; ++t) {
    const int slp = (sl == 0) ? 2 : sl - 1;   // (t-1) % 3
    // --- layer-0 xp: stage embedding rows into sHB (flag-independent) ---
    if (isXp && l == 0) {
      int u = tid - 256;
#pragma unroll
      for (int i = 0; i < 2; ++i) {
        int row = (u >> 4) + i * 16;
        int c0 = (u & 15) * 32;
        int tk = tok[(long)(bg * 32 + row) * 512 + t];
        const float* es = embedding + (long)tk * 512 + c0;
        u16 tmp[32];
#pragma unroll
        for (int q = 0; q < 8; ++q) {
          float4 v = *(const float4*)(es + q * 4);
          tmp[q * 4 + 0] = f2bf(v.x); tmp[q * 4 + 1] = f2bf(v.y);
          tmp[q * 4 + 2] = f2bf(v.z); tmp[q * 4 + 3] = f2bf(v.w);
        }
#pragma unroll
        for (int q = 0; q < 4; ++q) {
          int grp = (c0 >> 3) + q;
          *(u32x4*)&sHB[row * 512 + ((grp ^ (row & 7)) * 8)] = *(u32x4*)&tmp[q * 8];
        }
      }
    }
    asm volatile("" ::: "memory");
    // --- poll (per-wave minimal conditions) ---
    if (!(isXp && l == 0)) {
      const unsigned* fb;
      int tgt;
      if (isXp) { fb = flags + (l - 1) * 64 + bg * 16; tgt = t + 2; }
      else if (lane >= 32 && l < 2) { fb = flags + (l + 1) * 64 + bg * 16; tgt = t - 1; }
      else { fb = myflags; tgt = t + 1; }
      const unsigned* fp = fb + (lane & 15);
      int it = 0;
      bool ok;
      do {
        unsigned v = __hip_atomic_load(fp, __ATOMIC_RELAXED, __HIP_MEMORY_SCOPE_AGENT);
        ok = (bool)__all((int)v >= tgt);
        if (!ok) __builtin_amdgcn_s_sleep(2);
      } while (!ok && ++it < (1 << 22));
    }
    asm volatile("" ::: "memory");
    // --- stage h slices (bypass loads from ring) ---
    if (!isXp || l > 0) {
      const unsigned* hsrc = (!isXp ? (const unsigned*)ringL + slp * 32768
                                    : ringB + sl * 32768) + bg * 32 * 256;
      u16* dstL = !isXp ? sHA : sHB;
      int u = isXp ? tid - 256 : tid;
      u32x4 vv[8];
#pragma unroll
      for (int i = 0; i < 8; ++i) {
        int uu = u + i * 256;
        const unsigned* src = hsrc + (uu >> 6) * 256 + (uu & 63) * 4;
        asm volatile("global_load_dwordx4 %0, %1, off sc0 sc1"
                     : "=&v"(vv[i]) : "v"(src) : "memory");
      }
      asm volatile("s_waitcnt vmcnt(0)" ::: "memory");
      __builtin_amdgcn_sched_barrier(0);
#pragma unroll
      for (int i = 0; i < 8; ++i) {
        int uu = u + i * 256;
        int row = uu >> 6, c8 = uu & 63;
        *(u32x4*)&dstL[row * 512 + ((c8 ^ (row & 7)) * 8)] = vv[i];
      }
    }
    __syncthreads();
    // --- MFMA over K=512 from register-resident weights ---
    f32x4 acc[3] = {};
    const u16* sH = isXp ? sHB : sHA;
    const int abase = (mw * 16 + rr) * 512;
    const int axor = (mw * 16 + rr) & 7;
#pragma unroll
    for (int ks = 0; ks < 16; ++ks) {
      bf16x8 af = __builtin_bit_cast(
          bf16x8, *(const u32x4*)&sH[abase + (((ks * 4 + kq) ^ axor) * 8)]);
#pragma unroll
      for (int g = 0; g < 3; ++g)
        acc[g] = __builtin_amdgcn_mfma_f32_16x16x32_bf16(
            af, __builtin_bit_cast(bf16x8, wf[g][ks]), acc[g], 0, 0, 0);
    }
    if (isXp) {
#pragma unroll
      for (int g = 0; g < 3; ++g)
#pragma unroll
        for (int rg = 0; rg < 4; ++rg)
          sXP[(bL + rg) * 101 + g * 32 + chL] = acc[g][rg] + bh[g];
    }
    __syncthreads();
    // --- gates + publish (gh waves) ---
    if (!isXp) {
      unsigned pk[4];
#pragma unroll
      for (int rg = 0; rg < 4; ++rg) {
        float xr = sXP[(bL + rg) * 101 + chL];
        float xz = sXP[(bL + rg) * 101 + 32 + chL];
        float xn = sXP[(bL + rg) * 101 + 64 + chL];
        float r = 1.f / (1.f + __expf(-(xr + acc[0][rg] + bh[0])));
        float z = 1.f / (1.f + __expf(-(xz + acc[1][rg] + bh[1])));
        float n = tanhf(xn + r * (acc[2][rg] + bh[2]));
        float h2 = (1.f - z) * n + z * mh[rg];
        mh[rg] = h2;
        u16 hb = f2bf(h2);
        pk[rg] = (unsigned)hb;
        if (l == 2) xout2[((long)(b0 + rg) * 512 + t) * 512 + ch] = hb;
      }
#pragma unroll
      for (int rg = 0; rg < 4; ++rg) {
        unsigned prt = (unsigned)__shfl_xor((int)pk[rg], 1);
        if (!(cl & 1))
          __hip_atomic_store(&ringL[sl * 32768 + (b0 + rg) * 256 + (ch >> 1)],
                             pk[rg] | (prt << 16), __ATOMIC_RELAXED,
                             __HIP_MEMORY_SCOPE_AGENT);
      }
      asm volatile("s_waitcnt vmcnt(0)" ::: "memory");
    }
    __syncthreads();
    if (tid == 0)
      __hip_atomic_store(&myflags[cg], (unsigned)(t + 2), __ATOMIC_RELAXED,
                         __HIP_MEMORY_SCOPE_AGENT);
    sl = (sl == 2) ? 0 : sl + 1;
  }
  if (!isXp) {
#pragma unroll
    for (int rg = 0; rg < 4; ++rg)
      hfin[(long)l * 65536 + (long)(b0 + rg) * 512 + ch] = mh[rg];
  }
}

extern "C" void kernel_launch(void* const* d_in, const int* in_sizes, int n_in,
                              void* d_out, int out_size, void* d_ws, size_t ws_size,
                              hipStream_t stream) {
  const int* padded    = (const int*)d_in[0];
  const float* enc     = (const float*)d_in[2];
  const float* hidden  = (const float*)d_in[3];
  const float* embedding = (const float*)d_in[4];
  const float* w_ih    = (const float*)d_in[5];
  const float* w_hh    = (const float*)d_in[6];
  const float* b_ih    = (const float*)d_in[7];
  const float* b_hh    = (const float*)d_in[8];
  const float* attn_w  = (const float*)d_in[9];
  const float* attn_b  = (const float*)d_in[10];
  const float* out_w   = (const float*)d_in[11];
  const float* out_b   = (const float*)d_in[12];

  if (ws_size < 280204288ULL) return;   // ws budget guard

  char* ws = (char*)d_ws;
  u16* W_IH   = (u16*)(ws + 0);               // 3*1536*512 bf16
  u16* W_HH   = (u16*)(ws + 4718592);
  u16* ATTN_W = (u16*)(ws + 9437184);         // 512*1024 bf16
  u16* OUT_W  = (u16*)(ws + 10485760);        // 100*512 bf16
  unsigned* FLAGS = (unsigned*)(ws + 10588160);   // 3*64 u32 (1 KB slot)
  unsigned* RING  = (unsigned*)(ws + 10589184);   // 3*3*128*256 u32 = 1.125 MB
  u16* XA     = (u16*)(ws + 11768832);        // context bf16, 64 MB
  u16* XB     = (u16*)(ws + 78877696);        // dec = layer-2 output, 64 MB
  u16* ENCT   = (u16*)(ws + 145986560);       // enc^T bf16, 64 MB
  u16* AMASK  = (u16*)(ws + 213095424);       // tanh-masked / softmax-bf16 alias, 64 MB
  u16* ATTN_BF = AMASK;

  float* out_logits = (float*)d_out;                 // 65536*100
  float* out_h      = out_logits + 6553600;          // 3*128*512
  float* out_attn   = out_h + 196608;                // 128*512*512

  zero_flags<<<1, 256, 0, stream>>>(FLAGS, 192);
  cvt_f32_bf16<<<512, 256, 0, stream>>>(w_ih, W_IH, 2359296 / 4);
  cvt_f32_bf16<<<512, 256, 0, stream>>>(w_hh, W_HH, 2359296 / 4);
  cvt_f32_bf16<<<256, 256, 0, stream>>>(attn_w, ATTN_W, 524288 / 4);
  cvt_f32_bf16<<<64, 256, 0, stream>>>(out_w, OUT_W, 51200 / 4);
  // pre-GRU: also provides the L2 scrub traffic before ring bypass ops
  transpose_enc<<<dim3(8, 8, 128), 256, 0, stream>>>(enc, ENCT);

  gru_wave<<<192, 512, 0, stream>>>(
      padded, embedding, W_IH, W_HH, b_ih, b_hh, hidden,
      RING, FLAGS, XB, out_h);

  // attention (scores GEMM converts f32 enc in staging; no ENC_BF buffer)
  gemm_xwt<1, 1><<<dim3(4, 4, 128), 256, 0, stream>>>(
      XB, nullptr, (const u16*)enc, nullptr, out_attn, nullptr,
      512, 512, 512, 262144, 262144, 262144, 0.044194173824159216f, 512);
  softmax_rows<<<16384, 256, 0, stream>>>(out_attn, ATTN_BF);
  gemm_xwt<2, 0><<<dim3(4, 4, 128), 256, 0, stream>>>(
      ATTN_BF, nullptr, ENCT, nullptr, XA, nullptr,
      512, 512, 512, 262144, 262144, 262144, 1.f, 512);
  gemm_xwt<3, 0><<<dim3(4, 512, 1), 256, 0, stream>>>(
      XB, XA, ATTN_W, attn_b, AMASK, XB,
      512, 1024, 512, 0, 0, 0, 1.f, 512);
  gemm_xwt<4, 0><<<dim3(1, 512, 1), 256, 0, stream>>>(
      AMASK, nullptr, OUT_W, out_b, d_out, XB,
      100, 512, 512, 0, 0, 0, 1.f, 100);
}

// Round 6
// 5065.685 us; speedup vs baseline: 6.0596x; 1.0732x over previous
//
#include <hip/hip_runtime.h>

// Decoder: emb -> 3-layer GRU -> scaled-dot attention over encoder -> tanh(linear) -> logits
// Round 5: true register-resident weights.
//   r4 tell: VGPR_Count=128 & FETCH 814MB -> compiler re-loaded weights every phase
//   (one-shot asm pin doesn't forbid reload; launch_bounds(512,2) capped regs).
//   Fix: 4-wave WG (no mw weight duplication; each wave does 2 serial M-tiles) +
//   launch_bounds(256,1) (512-reg budget) + IN-LOOP asm "+v" pins (reload illegal).

typedef unsigned short u16;
typedef __attribute__((ext_vector_type(8))) __bf16 bf16x8;
typedef __attribute__((ext_vector_type(4))) float f32x4;
typedef __attribute__((ext_vector_type(4))) unsigned int u32x4;

#define D_ 512
#define S_ 512
#define SE_ 512
#define B_ 128
#define V_ 100
#define TD_ 1536

__device__ __forceinline__ float bf2f(u16 v) {
  unsigned u = ((unsigned)v) << 16;
  return __builtin_bit_cast(float, u);
}
__device__ __forceinline__ u16 f2bf(float f) {
  unsigned u = __builtin_bit_cast(unsigned, f);
  u += 0x7FFF + ((u >> 16) & 1);   // RNE
  return (u16)(u >> 16);
}

// ---------------- elementwise converts ----------------
__global__ __launch_bounds__(256) void cvt_f32_bf16(const float* __restrict__ src,
                                                    u16* __restrict__ dst, long n4) {
  long i = (long)blockIdx.x * 256 + threadIdx.x;
  long stride = (long)gridDim.x * 256;
  for (; i < n4; i += stride) {
    float4 v = ((const float4*)src)[i];
    unsigned long long p = (unsigned long long)f2bf(v.x) |
                           ((unsigned long long)f2bf(v.y) << 16) |
                           ((unsigned long long)f2bf(v.z) << 32) |
                           ((unsigned long long)f2bf(v.w) << 48);
    ((unsigned long long*)dst)[i] = p;
  }
}

// zero flags at the coherence point (bypass stores - no stale-L2 window)
__global__ __launch_bounds__(256) void zero_flags(unsigned* __restrict__ f, int n) {
  int i = blockIdx.x * 256 + threadIdx.x;
  if (i < n)
    __hip_atomic_store(&f[i], 0u, __ATOMIC_RELAXED, __HIP_MEMORY_SCOPE_AGENT);
}

// enc (B,SE,D) f32 -> encT (B,D,SE) bf16
__global__ __launch_bounds__(256) void transpose_enc(const float* __restrict__ enc,
                                                     u16* __restrict__ encT) {
  __shared__ u16 tile[64][72];
  int b = blockIdx.z, d0 = blockIdx.x * 64, se0 = blockIdx.y * 64;
  const float* src = enc + (long)b * SE_ * D_;
  int t = threadIdx.x;
  int r = t >> 2, cq = (t & 3) * 16;
#pragma unroll
  for (int j = 0; j < 4; ++j) {
    float4 v = *(const float4*)(src + (long)(se0 + r) * D_ + d0 + cq + j * 4);
    tile[r][cq + j * 4 + 0] = f2bf(v.x);
    tile[r][cq + j * 4 + 1] = f2bf(v.y);
    tile[r][cq + j * 4 + 2] = f2bf(v.z);
    tile[r][cq + j * 4 + 3] = f2bf(v.w);
  }
  __syncthreads();
  u16* dst = encT + (long)b * D_ * SE_;
  u16 ov[16];
#pragma unroll
  for (int j = 0; j < 16; ++j) ov[j] = tile[cq + j][r];
  *(u32x4*)(dst + (long)(d0 + r) * SE_ + se0 + cq) = *(u32x4*)&ov[0];
  *(u32x4*)(dst + (long)(d0 + r) * SE_ + se0 + cq + 8) = *(u32x4*)&ov[8];
}

// in-place fp32 softmax over 512-wide rows + bf16 copy
__global__ __launch_bounds__(256) void softmax_rows(float* __restrict__ sc,
                                                    u16* __restrict__ abf) {
  long row = (long)blockIdx.x * 4 + (threadIdx.x >> 6);
  int lane = threadIdx.x & 63;
  float* p = sc + row * 512;
  float4 v0 = ((const float4*)p)[lane * 2];
  float4 v1 = ((const float4*)p)[lane * 2 + 1];
  float vals[8] = {v0.x, v0.y, v0.z, v0.w, v1.x, v1.y, v1.z, v1.w};
  float m = vals[0];
#pragma unroll
  for (int j = 1; j < 8; ++j) m = fmaxf(m, vals[j]);
#pragma unroll
  for (int o = 32; o; o >>= 1) m = fmaxf(m, __shfl_xor(m, o, 64));
  float s = 0.f;
#pragma unroll
  for (int j = 0; j < 8; ++j) { vals[j] = __expf(vals[j] - m); s += vals[j]; }
#pragma unroll
  for (int o = 32; o; o >>= 1) s += __shfl_xor(s, o, 64);
  float inv = 1.f / s;
  u16 ob[8];
#pragma unroll
  for (int j = 0; j < 8; ++j) { vals[j] *= inv; ob[j] = f2bf(vals[j]); }
  float4 w0 = {vals[0], vals[1], vals[2], vals[3]};
  float4 w1 = {vals[4], vals[5], vals[6], vals[7]};
  ((float4*)p)[lane * 2] = w0;
  ((float4*)p)[lane * 2 + 1] = w1;
  *(u32x4*)(abf + row * 512 + lane * 8) = *(u32x4*)ob;
}

// ---------------- generic C = A(M,K) @ W(N,K)^T, bf16 in / f32 acc ----------------
// MODE 1: *scale -> f32 batched (scores; WF32: W is f32, cvt in staging)
// MODE 2: -> bf16 batched (context) MODE 3: split-K A, tanh(+bias)*mask -> bf16
// MODE 4: (+bias)*mask -> f32, col<N (logits)
template <int MODE, int WF32>
__global__ __launch_bounds__(256) void gemm_xwt(
    const u16* __restrict__ A1, const u16* __restrict__ A2, const u16* __restrict__ W,
    const float* __restrict__ bias, void* __restrict__ Cout, const u16* __restrict__ maskSrc,
    int N, int K, int K1, long sAb, long sWb, long sCb, float scale, int ldc) {
  __shared__ u16 sA[128][32];
  __shared__ u16 sW_[128][32];
  int bz = blockIdx.z;
  int n0 = blockIdx.x * 128, m0 = blockIdx.y * 128;
  const u16* Ab = A1 + (long)bz * sAb;
  int t = threadIdx.x, wave = t >> 6, lane = t & 63;
  int wm = (wave >> 1) * 64, wn = (wave & 1) * 64;
  f32x4 acc[4][4] = {};
  for (int kk = 0; kk < K; kk += 32) {
#pragma unroll
    for (int i = 0; i < 2; ++i) {
      int id = t + i * 256;
      int row = id >> 2, c8 = (id & 3) * 8;
      const u16* src;
      if (MODE == 3 && kk >= K1)
        src = A2 + (long)(m0 + row) * (K - K1) + (kk - K1) + c8;
      else
        src = Ab + (long)(m0 + row) * K1 + kk + c8;
      *(u32x4*)&sA[row][c8] = *(const u32x4*)src;
    }
#pragma unroll
    for (int i = 0; i < 2; ++i) {
      int id = t + i * 256;
      int row = id >> 2, c8 = (id & 3) * 8;
      if (WF32) {
        const float* wsrc = ((const float*)W) + (long)bz * sWb + (long)(n0 + row) * K + kk + c8;
        float4 va = *(const float4*)wsrc;
        float4 vb = *(const float4*)(wsrc + 4);
        u16 tmp[8] = {f2bf(va.x), f2bf(va.y), f2bf(va.z), f2bf(va.w),
                      f2bf(vb.x), f2bf(vb.y), f2bf(vb.z), f2bf(vb.w)};
        *(u32x4*)&sW_[row][c8] = *(u32x4*)tmp;
      } else {
        u32x4 v = {0u, 0u, 0u, 0u};
        if (n0 + row < N) v = *(const u32x4*)(W + (long)bz * sWb + (long)(n0 + row) * K + kk + c8);
        *(u32x4*)&sW_[row][c8] = v;
      }
    }
    __syncthreads();
    int k8 = (lane >> 4) * 8, rr = lane & 15;
    bf16x8 wf[4];
#pragma unroll
    for (int nt = 0; nt < 4; ++nt)
      wf[nt] = __builtin_bit_cast(bf16x8, *(const u32x4*)&sW_[wn + nt * 16 + rr][k8]);
#pragma unroll
    for (int mt = 0; mt < 4; ++mt) {
      bf16x8 af = __builtin_bit_cast(bf16x8, *(const u32x4*)&sA[wm + mt * 16 + rr][k8]);
#pragma unroll
      for (int nt = 0; nt < 4; ++nt)
        acc[mt][nt] = __builtin_amdgcn_mfma_f32_16x16x32_bf16(af, wf[nt], acc[mt][nt], 0, 0, 0);
    }
    __syncthreads();
  }
  int rq = (lane >> 4) * 4, cl = lane & 15;
#pragma unroll
  for (int mt = 0; mt < 4; ++mt) {
#pragma unroll
    for (int nt = 0; nt < 4; ++nt) {
#pragma unroll
      for (int rg = 0; rg < 4; ++rg) {
        int row = m0 + wm + mt * 16 + rq + rg;
        int col = n0 + wn + nt * 16 + cl;
        float v = acc[mt][nt][rg];
        if (MODE == 1) {
          ((float*)Cout)[(long)bz * sCb + (long)row * ldc + col] = v * scale;
        } else if (MODE == 2) {
          ((u16*)Cout)[(long)bz * sCb + (long)row * ldc + col] = f2bf(v);
        } else if (MODE == 3) {
          float mk = (bf2f(maskSrc[(long)row * D_]) != 0.f) ? 1.f : 0.f;
          ((u16*)Cout)[(long)row * ldc + col] = f2bf(tanhf(v + bias[col]) * mk);
        } else {
          if (col < N) {
            float mk = (bf2f(maskSrc[(long)row * D_]) != 0.f) ? 1.f : 0.f;
            ((float*)Cout)[(long)row * ldc + col] = (v + bias[col]) * mk;
          }
        }
      }
    }
  }
}

// ---------------- wavefront-pipelined 3-layer GRU ----------------
// grid 192 = l(3) x bg(4) x cg(16); 256 threads: waves 0-1 gh (nh=wave),
// waves 2-3 xp (nh=wave-2). Each wave: M=32 (2 serial M-tiles) x N=16 x 3 gates.
// Weights register-resident: wf[3][16] = 192 VGPRs/thread, NO duplication across
// waves, pinned IN-LOOP so reload-from-memory is illegal. launch_bounds(256,1).
// ring[l]: 3 slots x [128][256] u32 (packed bf16 pairs), IC-coherent bypass ops.
// flags[l][bg][cg] = t+2 after step t. Poll: gh own>=t+1 (lane<32) &
// above>=t-1 (lane>=32, l<2); xp below>=t+2 (l>0).
__global__ __launch_bounds__(256, 1) void gru_wave(
    const int* __restrict__ tok, const float* __restrict__ embedding,
    const u16* __restrict__ wih_all, const u16* __restrict__ whh_all,
    const float* __restrict__ bih_all, const float* __restrict__ bhh_all,
    const float* __restrict__ hidden,
    unsigned* __restrict__ ring, unsigned* __restrict__ flags,
    u16* __restrict__ xout2, float* __restrict__ hfin) {
  __shared__ u16 sHA[32 * 512];
  __shared__ u16 sHB[32 * 512];
  __shared__ float sXP[32 * 101];
  const int bid = blockIdx.x;
  const int l = bid >> 6;
  const int bg = (bid >> 4) & 3;
  const int cg = bid & 15;
  const int tid = threadIdx.x;
  const int wave = tid >> 6;          // 0..3
  const bool isXp = wave >= 2;
  const int nh = wave & 1;
  const int lane = tid & 63;
  const int rr = lane & 15, kq = lane >> 4;
  const int cl = lane & 15, rq = lane >> 4;
  const int chL = nh * 16 + cl;
  const int ch = cg * 32 + chL;       // this thread's output channel
  unsigned* myflags = flags + l * 64 + bg * 16;
  const u16* Wsrc = (isXp ? wih_all : whh_all) + (long)l * 786432;
  const float* bsrc = (isXp ? bih_all : bhh_all) + l * 1536;
  float bh[3];
#pragma unroll
  for (int g = 0; g < 3; ++g) bh[g] = bsrc[g * 512 + ch];
  unsigned* ringL = ring + l * 3 * 32768;
  const unsigned* ringB = ring + (l - 1) * 3 * 32768;   // valid for l>0

  // --- load weight B-fragments into registers ONCE (192 VGPRs, no wave dup) ---
  u32x4 wf[3][16];
#pragma unroll
  for (int g = 0; g < 3; ++g) {
    const u16* wrow = Wsrc + ((long)(g * 512 + cg * 32 + nh * 16 + rr)) * 512 + kq * 8;
#pragma unroll
    for (int ks = 0; ks < 16; ++ks) wf[g][ks] = *(const u32x4*)(wrow + ks * 32);
  }

  // --- init: fp32 master + publish h[-1] into slot 2 ---
  float mh[2][4] = {};
  if (!isXp) {
#pragma unroll
    for (int mt = 0; mt < 2; ++mt) {
      unsigned pk[4];
#pragma unroll
      for (int rg = 0; rg < 4; ++rg) {
        int bb = bg * 32 + mt * 16 + rq * 4 + rg;
        mh[mt][rg] = hidden[(long)l * 65536 + (long)bb * 512 + ch];
        pk[rg] = (unsigned)f2bf(mh[mt][rg]);
      }
#pragma unroll
      for (int rg = 0; rg < 4; ++rg) {
        unsigned prt = (unsigned)__shfl_xor((int)pk[rg], 1);
        if (!(cl & 1))
          __hip_atomic_store(
              &ringL[2 * 32768 + (bg * 32 + mt * 16 + rq * 4 + rg) * 256 + (ch >> 1)],
              pk[rg] | (prt << 16), __ATOMIC_RELAXED, __HIP_MEMORY_SCOPE_AGENT);
      }
    }
  }
  asm volatile("s_waitcnt vmcnt(0)" ::: "memory");
  __syncthreads();
  if (tid == 0)
    __hip_atomic_store(&myflags[cg], 1u, __ATOMIC_RELAXED, __HIP_MEMORY_SCOPE_AGENT);

  int sl = 0;   // t % 3
#pragma unroll 1
  for (int t = 0; t < S_; ++t) {
    const int slp = (sl == 0) ? 2 : sl - 1;   // (t-1) % 3
    // --- IN-LOOP pin: weights must be materialized in regs here every phase;
    //     reloading from memory after this point is illegal for the compiler ---
#pragma unroll
    for (int g = 0; g < 3; ++g)
#pragma unroll
      for (int ks = 0; ks < 16; ++ks) asm volatile("" : "+v"(wf[g][ks]));

    // --- layer-0 xp: stage embedding rows into sHB (flag-independent) ---
    if (isXp && l == 0) {
      int u = tid - 128;
#pragma unroll
      for (int i = 0; i < 4; ++i) {
        int task = u + i * 128;
        int row = task >> 4;
        int c0 = (task & 15) * 32;
        int tk = tok[(long)(bg * 32 + row) * 512 + t];
        const float* es = embedding + (long)tk * 512 + c0;
        u16 tmp[32];
#pragma unroll
        for (int q = 0; q < 8; ++q) {
          float4 v = *(const float4*)(es + q * 4);
          tmp[q * 4 + 0] = f2bf(v.x); tmp[q * 4 + 1] = f2bf(v.y);
          tmp[q * 4 + 2] = f2bf(v.z); tmp[q * 4 + 3] = f2bf(v.w);
        }
#pragma unroll
        for (int q = 0; q < 4; ++q) {
          int grp = (c0 >> 3) + q;
          *(u32x4*)&sHB[row * 512 + ((grp ^ (row & 7)) * 8)] = *(u32x4*)&tmp[q * 8];
        }
      }
    }
    asm volatile("" ::: "memory");
    // --- poll (per-wave minimal conditions) ---
    if (!(isXp && l == 0)) {
      const unsigned* fb;
      int tgt;
      if (isXp) { fb = flags + (l - 1) * 64 + bg * 16; tgt = t + 2; }
      else if (lane >= 32 && l < 2) { fb = flags + (l + 1) * 64 + bg * 16; tgt = t - 1; }
      else { fb = myflags; tgt = t + 1; }
      const unsigned* fp = fb + (lane & 15);
      int it = 0;
      bool ok;
      do {
        unsigned v = __hip_atomic_load(fp, __ATOMIC_RELAXED, __HIP_MEMORY_SCOPE_AGENT);
        ok = (bool)__all((int)v >= tgt);
        if (!ok) __builtin_amdgcn_s_sleep(2);
      } while (!ok && ++it < (1 << 22));
    }
    asm volatile("" ::: "memory");
    // --- stage h slices (bypass loads from ring): 128 thr x 16 x 16B per half ---
    if (!isXp || l > 0) {
      const unsigned* hsrc = (!isXp ? (const unsigned*)ringL + slp * 32768
                                    : ringB + sl * 32768) + bg * 32 * 256;
      u16* dstL = !isXp ? sHA : sHB;
      int u = isXp ? tid - 128 : tid;
      u32x4 vv[16];
#pragma unroll
      for (int i = 0; i < 16; ++i) {
        int uu = u + i * 128;
        const unsigned* src = hsrc + (uu >> 6) * 256 + (uu & 63) * 4;
        asm volatile("global_load_dwordx4 %0, %1, off sc0 sc1"
                     : "=&v"(vv[i]) : "v"(src) : "memory");
      }
      asm volatile("s_waitcnt vmcnt(0)" ::: "memory");
      __builtin_amdgcn_sched_barrier(0);
#pragma unroll
      for (int i = 0; i < 16; ++i) {
        int uu = u + i * 128;
        int row = uu >> 6, c8 = uu & 63;
        *(u32x4*)&dstL[row * 512 + ((c8 ^ (row & 7)) * 8)] = vv[i];
      }
    }
    __syncthreads();
    // --- MFMA: 2 serial M-tiles x 3 gates x K=512, weights from registers ---
    f32x4 acc[2][3] = {};
    const u16* sH = isXp ? sHB : sHA;
#pragma unroll
    for (int mt = 0; mt < 2; ++mt) {
      const int abase = (mt * 16 + rr) * 512;
      const int axor = (mt * 16 + rr) & 7;
#pragma unroll
      for (int ks = 0; ks < 16; ++ks) {
        bf16x8 af = __builtin_bit_cast(
            bf16x8, *(const u32x4*)&sH[abase + (((ks * 4 + kq) ^ axor) * 8)]);
#pragma unroll
        for (int g = 0; g < 3; ++g)
          acc[mt][g] = __builtin_amdgcn_mfma_f32_16x16x32_bf16(
              af, __builtin_bit_cast(bf16x8, wf[g][ks]), acc[mt][g], 0, 0, 0);
      }
    }
    if (isXp) {
#pragma unroll
      for (int mt = 0; mt < 2; ++mt)
#pragma unroll
        for (int g = 0; g < 3; ++g)
#pragma unroll
          for (int rg = 0; rg < 4; ++rg)
            sXP[(mt * 16 + rq * 4 + rg) * 101 + g * 32 + chL] = acc[mt][g][rg] + bh[g];
    }
    __syncthreads();
    // --- gates + publish (gh waves) ---
    if (!isXp) {
#pragma unroll
      for (int mt = 0; mt < 2; ++mt) {
        unsigned pk[4];
#pragma unroll
        for (int rg = 0; rg < 4; ++rg) {
          int rloc = mt * 16 + rq * 4 + rg;
          float xr = sXP[rloc * 101 + chL];
          float xz = sXP[rloc * 101 + 32 + chL];
          float xn = sXP[rloc * 101 + 64 + chL];
          float r = 1.f / (1.f + __expf(-(xr + acc[mt][0][rg] + bh[0])));
          float z = 1.f / (1.f + __expf(-(xz + acc[mt][1][rg] + bh[1])));
          float n = tanhf(xn + r * (acc[mt][2][rg] + bh[2]));
          float h2 = (1.f - z) * n + z * mh[mt][rg];
          mh[mt][rg] = h2;
          u16 hb = f2bf(h2);
          pk[rg] = (unsigned)hb;
          if (l == 2) xout2[((long)(bg * 32 + rloc) * 512 + t) * 512 + ch] = hb;
        }
#pragma unroll
        for (int rg = 0; rg < 4; ++rg) {
          unsigned prt = (unsigned)__shfl_xor((int)pk[rg], 1);
          if (!(cl & 1))
            __hip_atomic_store(
                &ringL[sl * 32768 + (bg * 32 + mt * 16 + rq * 4 + rg) * 256 + (ch >> 1)],
                pk[rg] | (prt << 16), __ATOMIC_RELAXED, __HIP_MEMORY_SCOPE_AGENT);
        }
      }
      asm volatile("s_waitcnt vmcnt(0)" ::: "memory");
    }
    __syncthreads();
    if (tid == 0)
      __hip_atomic_store(&myflags[cg], (unsigned)(t + 2), __ATOMIC_RELAXED,
                         __HIP_MEMORY_SCOPE_AGENT);
    sl = (sl == 2) ? 0 : sl + 1;
  }
  if (!isXp) {
#pragma unroll
    for (int mt = 0; mt < 2; ++mt)
#pragma unroll
      for (int rg = 0; rg < 4; ++rg)
        hfin[(long)l * 65536 + (long)(bg * 32 + mt * 16 + rq * 4 + rg) * 512 + ch] =
            mh[mt][rg];
  }
}

extern "C" void kernel_launch(void* const* d_in, const int* in_sizes, int n_in,
                              void* d_out, int out_size, void* d_ws, size_t ws_size,
                              hipStream_t stream) {
  const int* padded    = (const int*)d_in[0];
  const float* enc     = (const float*)d_in[2];
  const float* hidden  = (const float*)d_in[3];
  const float* embedding = (const float*)d_in[4];
  const float* w_ih    = (const float*)d_in[5];
  const float* w_hh    = (const float*)d_in[6];
  const float* b_ih    = (const float*)d_in[7];
  const float* b_hh    = (const float*)d_in[8];
  const float* attn_w  = (const float*)d_in[9];
  const float* attn_b  = (const float*)d_in[10];
  const float* out_w   = (const float*)d_in[11];
  const float* out_b   = (const float*)d_in[12];

  if (ws_size < 280204288ULL) return;   // ws budget guard

  char* ws = (char*)d_ws;
  u16* W_IH   = (u16*)(ws + 0);               // 3*1536*512 bf16
  u16* W_HH   = (u16*)(ws + 4718592);
  u16* ATTN_W = (u16*)(ws + 9437184);         // 512*1024 bf16
  u16* OUT_W  = (u16*)(ws + 10485760);        // 100*512 bf16
  unsigned* FLAGS = (unsigned*)(ws + 10588160);   // 3*64 u32 (1 KB slot)
  unsigned* RING  = (unsigned*)(ws + 10589184);   // 3*3*128*256 u32 = 1.125 MB
  u16* XA     = (u16*)(ws + 11768832);        // context bf16, 64 MB
  u16* XB     = (u16*)(ws + 78877696);        // dec = layer-2 output, 64 MB
  u16* ENCT   = (u16*)(ws + 145986560);       // enc^T bf16, 64 MB
  u16* AMASK  = (u16*)(ws + 213095424);       // tanh-masked / softmax-bf16 alias, 64 MB
  u16* ATTN_BF = AMASK;

  float* out_logits = (float*)d_out;                 // 65536*100
  float* out_h      = out_logits + 6553600;          // 3*128*512
  float* out_attn   = out_h + 196608;                // 128*512*512

  zero_flags<<<1, 256, 0, stream>>>(FLAGS, 192);
  cvt_f32_bf16<<<512, 256, 0, stream>>>(w_ih, W_IH, 2359296 / 4);
  cvt_f32_bf16<<<512, 256, 0, stream>>>(w_hh, W_HH, 2359296 / 4);
  cvt_f32_bf16<<<256, 256, 0, stream>>>(attn_w, ATTN_W, 524288 / 4);
  cvt_f32_bf16<<<64, 256, 0, stream>>>(out_w, OUT_W, 51200 / 4);
  // pre-GRU: also provides the L2 scrub traffic before ring bypass ops
  transpose_enc<<<dim3(8, 8, 128), 256, 0, stream>>>(enc, ENCT);

  gru_wave<<<192, 256, 0, stream>>>(
      padded, embedding, W_IH, W_HH, b_ih, b_hh, hidden,
      RING, FLAGS, XB, out_h);

  // attention (scores GEMM converts f32 enc in staging; no ENC_BF buffer)
  gemm_xwt<1, 1><<<dim3(4, 4, 128), 256, 0, stream>>>(
      XB, nullptr, (const u16*)enc, nullptr, out_attn, nullptr,
      512, 512, 512, 262144, 262144, 262144, 0.044194173824159216f, 512);
  softmax_rows<<<16384, 256, 0, stream>>>(out_attn, ATTN_BF);
  gemm_xwt<2, 0><<<dim3(4, 4, 128), 256, 0, stream>>>(
      ATTN_BF, nullptr, ENCT, nullptr, XA, nullptr,
      512, 512, 512, 262144, 262144, 262144, 1.f, 512);
  gemm_xwt<3, 0><<<dim3(4, 512, 1), 256, 0, stream>>>(
      XB, XA, ATTN_W, attn_b, AMASK, XB,
      512, 1024, 512, 0, 0, 0, 1.f, 512);
  gemm_xwt<4, 0><<<dim3(1, 512, 1), 256, 0, stream>>>(
      AMASK, nullptr, OUT_W, out_b, d_out, XB,
      100, 512, 512, 0, 0, 0, 1.f, 100);
}

// Round 7
// 4703.557 us; speedup vs baseline: 6.5261x; 1.0770x over previous
//
#include <hip/hip_runtime.h>

// Decoder: emb -> 3-layer GRU -> scaled-dot attention over encoder -> tanh(linear) -> logits
// Round 6: K-split weight residency. r5 tell: VGPR=180 < 192 -> RA never holds full-K
// weight frags. Fix: 8 waves (gh: nh x kh, xp: nh x kh), each thread wf[3][8] = 96 VGPRs
// (peak ~150 incl staging) -> residency is now cheap for the RA. kh=1 partials combined
// via LDS (sPART). l=2 xout stores moved AFTER flag publish (off the vmcnt drain path).

typedef unsigned short u16;
typedef __attribute__((ext_vector_type(8))) __bf16 bf16x8;
typedef __attribute__((ext_vector_type(4))) float f32x4;
typedef __attribute__((ext_vector_type(4))) unsigned int u32x4;

#define D_ 512
#define S_ 512
#define SE_ 512
#define B_ 128
#define V_ 100
#define TD_ 1536

__device__ __forceinline__ float bf2f(u16 v) {
  unsigned u = ((unsigned)v) << 16;
  return __builtin_bit_cast(float, u);
}
__device__ __forceinline__ u16 f2bf(float f) {
  unsigned u = __builtin_bit_cast(unsigned, f);
  u += 0x7FFF + ((u >> 16) & 1);   // RNE
  return (u16)(u >> 16);
}

// ---------------- elementwise converts ----------------
__global__ __launch_bounds__(256) void cvt_f32_bf16(const float* __restrict__ src,
                                                    u16* __restrict__ dst, long n4) {
  long i = (long)blockIdx.x * 256 + threadIdx.x;
  long stride = (long)gridDim.x * 256;
  for (; i < n4; i += stride) {
    float4 v = ((const float4*)src)[i];
    unsigned long long p = (unsigned long long)f2bf(v.x) |
                           ((unsigned long long)f2bf(v.y) << 16) |
                           ((unsigned long long)f2bf(v.z) << 32) |
                           ((unsigned long long)f2bf(v.w) << 48);
    ((unsigned long long*)dst)[i] = p;
  }
}

// zero flags at the coherence point (bypass stores - no stale-L2 window)
__global__ __launch_bounds__(256) void zero_flags(unsigned* __restrict__ f, int n) {
  int i = blockIdx.x * 256 + threadIdx.x;
  if (i < n)
    __hip_atomic_store(&f[i], 0u, __ATOMIC_RELAXED, __HIP_MEMORY_SCOPE_AGENT);
}

// enc (B,SE,D) f32 -> encT (B,D,SE) bf16
__global__ __launch_bounds__(256) void transpose_enc(const float* __restrict__ enc,
                                                     u16* __restrict__ encT) {
  __shared__ u16 tile[64][72];
  int b = blockIdx.z, d0 = blockIdx.x * 64, se0 = blockIdx.y * 64;
  const float* src = enc + (long)b * SE_ * D_;
  int t = threadIdx.x;
  int r = t >> 2, cq = (t & 3) * 16;
#pragma unroll
  for (int j = 0; j < 4; ++j) {
    float4 v = *(const float4*)(src + (long)(se0 + r) * D_ + d0 + cq + j * 4);
    tile[r][cq + j * 4 + 0] = f2bf(v.x);
    tile[r][cq + j * 4 + 1] = f2bf(v.y);
    tile[r][cq + j * 4 + 2] = f2bf(v.z);
    tile[r][cq + j * 4 + 3] = f2bf(v.w);
  }
  __syncthreads();
  u16* dst = encT + (long)b * D_ * SE_;
  u16 ov[16];
#pragma unroll
  for (int j = 0; j < 16; ++j) ov[j] = tile[cq + j][r];
  *(u32x4*)(dst + (long)(d0 + r) * SE_ + se0 + cq) = *(u32x4*)&ov[0];
  *(u32x4*)(dst + (long)(d0 + r) * SE_ + se0 + cq + 8) = *(u32x4*)&ov[8];
}

// in-place fp32 softmax over 512-wide rows + bf16 copy
__global__ __launch_bounds__(256) void softmax_rows(float* __restrict__ sc,
                                                    u16* __restrict__ abf) {
  long row = (long)blockIdx.x * 4 + (threadIdx.x >> 6);
  int lane = threadIdx.x & 63;
  float* p = sc + row * 512;
  float4 v0 = ((const float4*)p)[lane * 2];
  float4 v1 = ((const float4*)p)[lane * 2 + 1];
  float vals[8] = {v0.x, v0.y, v0.z, v0.w, v1.x, v1.y, v1.z, v1.w};
  float m = vals[0];
#pragma unroll
  for (int j = 1; j < 8; ++j) m = fmaxf(m, vals[j]);
#pragma unroll
  for (int o = 32; o; o >>= 1) m = fmaxf(m, __shfl_xor(m, o, 64));
  float s = 0.f;
#pragma unroll
  for (int j = 0; j < 8; ++j) { vals[j] = __expf(vals[j] - m); s += vals[j]; }
#pragma unroll
  for (int o = 32; o; o >>= 1) s += __shfl_xor(s, o, 64);
  float inv = 1.f / s;
  u16 ob[8];
#pragma unroll
  for (int j = 0; j < 8; ++j) { vals[j] *= inv; ob[j] = f2bf(vals[j]); }
  float4 w0 = {vals[0], vals[1], vals[2], vals[3]};
  float4 w1 = {vals[4], vals[5], vals[6], vals[7]};
  ((float4*)p)[lane * 2] = w0;
  ((float4*)p)[lane * 2 + 1] = w1;
  *(u32x4*)(abf + row * 512 + lane * 8) = *(u32x4*)ob;
}

// ---------------- generic C = A(M,K) @ W(N,K)^T, bf16 in / f32 acc ----------------
// MODE 1: *scale -> f32 batched (scores; WF32: W is f32, cvt in staging)
// MODE 2: -> bf16 batched (context) MODE 3: split-K A, tanh(+bias)*mask -> bf16
// MODE 4: (+bias)*mask -> f32, col<N (logits)
template <int MODE, int WF32>
__global__ __launch_bounds__(256) void gemm_xwt(
    const u16* __restrict__ A1, const u16* __restrict__ A2, const u16* __restrict__ W,
    const float* __restrict__ bias, void* __restrict__ Cout, const u16* __restrict__ maskSrc,
    int N, int K, int K1, long sAb, long sWb, long sCb, float scale, int ldc) {
  __shared__ u16 sA[128][32];
  __shared__ u16 sW_[128][32];
  int bz = blockIdx.z;
  int n0 = blockIdx.x * 128, m0 = blockIdx.y * 128;
  const u16* Ab = A1 + (long)bz * sAb;
  int t = threadIdx.x, wave = t >> 6, lane = t & 63;
  int wm = (wave >> 1) * 64, wn = (wave & 1) * 64;
  f32x4 acc[4][4] = {};
  for (int kk = 0; kk < K; kk += 32) {
#pragma unroll
    for (int i = 0; i < 2; ++i) {
      int id = t + i * 256;
      int row = id >> 2, c8 = (id & 3) * 8;
      const u16* src;
      if (MODE == 3 && kk >= K1)
        src = A2 + (long)(m0 + row) * (K - K1) + (kk - K1) + c8;
      else
        src = Ab + (long)(m0 + row) * K1 + kk + c8;
      *(u32x4*)&sA[row][c8] = *(const u32x4*)src;
    }
#pragma unroll
    for (int i = 0; i < 2; ++i) {
      int id = t + i * 256;
      int row = id >> 2, c8 = (id & 3) * 8;
      if (WF32) {
        const float* wsrc = ((const float*)W) + (long)bz * sWb + (long)(n0 + row) * K + kk + c8;
        float4 va = *(const float4*)wsrc;
        float4 vb = *(const float4*)(wsrc + 4);
        u16 tmp[8] = {f2bf(va.x), f2bf(va.y), f2bf(va.z), f2bf(va.w),
                      f2bf(vb.x), f2bf(vb.y), f2bf(vb.z), f2bf(vb.w)};
        *(u32x4*)&sW_[row][c8] = *(u32x4*)tmp;
      } else {
        u32x4 v = {0u, 0u, 0u, 0u};
        if (n0 + row < N) v = *(const u32x4*)(W + (long)bz * sWb + (long)(n0 + row) * K + kk + c8);
        *(u32x4*)&sW_[row][c8] = v;
      }
    }
    __syncthreads();
    int k8 = (lane >> 4) * 8, rr = lane & 15;
    bf16x8 wf[4];
#pragma unroll
    for (int nt = 0; nt < 4; ++nt)
      wf[nt] = __builtin_bit_cast(bf16x8, *(const u32x4*)&sW_[wn + nt * 16 + rr][k8]);
#pragma unroll
    for (int mt = 0; mt < 4; ++mt) {
      bf16x8 af = __builtin_bit_cast(bf16x8, *(const u32x4*)&sA[wm + mt * 16 + rr][k8]);
#pragma unroll
      for (int nt = 0; nt < 4; ++nt)
        acc[mt][nt] = __builtin_amdgcn_mfma_f32_16x16x32_bf16(af, wf[nt], acc[mt][nt], 0, 0, 0);
    }
    __syncthreads();
  }
  int rq = (lane >> 4) * 4, cl = lane & 15;
#pragma unroll
  for (int mt = 0; mt < 4; ++mt) {
#pragma unroll
    for (int nt = 0; nt < 4; ++nt) {
#pragma unroll
      for (int rg = 0; rg < 4; ++rg) {
        int row = m0 + wm + mt * 16 + rq + rg;
        int col = n0 + wn + nt * 16 + cl;
        float v = acc[mt][nt][rg];
        if (MODE == 1) {
          ((float*)Cout)[(long)bz * sCb + (long)row * ldc + col] = v * scale;
        } else if (MODE == 2) {
          ((u16*)Cout)[(long)bz * sCb + (long)row * ldc + col] = f2bf(v);
        } else if (MODE == 3) {
          float mk = (bf2f(maskSrc[(long)row * D_]) != 0.f) ? 1.f : 0.f;
          ((u16*)Cout)[(long)row * ldc + col] = f2bf(tanhf(v + bias[col]) * mk);
        } else {
          if (col < N) {
            float mk = (bf2f(maskSrc[(long)row * D_]) != 0.f) ? 1.f : 0.f;
            ((float*)Cout)[(long)row * ldc + col] = (v + bias[col]) * mk;
          }
        }
      }
    }
  }
}

// ---------------- wavefront-pipelined 3-layer GRU, K-split ----------------
// grid 192 = l(3) x bg(4) x cg(16); 512 thr = 8 waves:
//   waves 0-3: gh, (nh = (w>>1)&1, kh = w&1); waves 4-7: xp, same sub-layout.
// Each thread: wf[3][8] = 96 VGPRs (K-half), resident across the whole t-loop.
// kh=1 partial sums -> sPART (16x17 f32 tiles); kh=0 combines after barrier.
// ring[l]: 3 slots x [128][256] u32 packed bf16 pairs, bypass (sc0 sc1) ops.
// flags[l][bg][cg]=t+2 after step t. Polls: gh lane<32 own>=t+1, gh lane>=32
// above>=t-1 (l<2); xp below>=t+2 (l>0). l=2 xout stores AFTER flag.
__global__ __launch_bounds__(512, 1) void gru_wave(
    const int* __restrict__ tok, const float* __restrict__ embedding,
    const u16* __restrict__ wih_all, const u16* __restrict__ whh_all,
    const float* __restrict__ bih_all, const float* __restrict__ bhh_all,
    const float* __restrict__ hidden,
    unsigned* __restrict__ ring, unsigned* __restrict__ flags,
    u16* __restrict__ xout2, float* __restrict__ hfin) {
  __shared__ u16 sHA[32 * 512];
  __shared__ u16 sHB[32 * 512];
  __shared__ float sXP[32 * 101];
  __shared__ float sPART[24 * 272];
  const int bid = blockIdx.x;
  const int l = bid >> 6;
  const int bg = (bid >> 4) & 3;
  const int cg = bid & 15;
  const int tid = threadIdx.x;
  const int wave = tid >> 6;          // 0..7
  const bool isXp = wave >= 4;
  const int nh = (wave >> 1) & 1;
  const int kh = wave & 1;
  const int lane = tid & 63;
  const int rr = lane & 15, kq = lane >> 4;
  const int cl = rr, rq = kq;
  const int chL = nh * 16 + cl;
  const int ch = cg * 32 + chL;       // this thread's output channel
  unsigned* myflags = flags + l * 64 + bg * 16;
  const u16* Wsrc = (isXp ? wih_all : whh_all) + (long)l * 786432;
  const float* bsrc = (isXp ? bih_all : bhh_all) + l * 1536;
  float bh[3];
#pragma unroll
  for (int g = 0; g < 3; ++g) bh[g] = bsrc[g * 512 + ch];
  unsigned* ringL = ring + l * 3 * 32768;
  const unsigned* ringB = ring + (l - 1) * 3 * 32768;   // valid for l>0

  // --- load this wave's K-half weight fragments ONCE: 24 x u32x4 = 96 VGPRs ---
  u32x4 wf[3][8];
#pragma unroll
  for (int g = 0; g < 3; ++g) {
    const u16* wrow =
        Wsrc + ((long)(g * 512 + cg * 32 + nh * 16 + rr)) * 512 + kh * 256 + kq * 8;
#pragma unroll
    for (int ks = 0; ks < 8; ++ks) wf[g][ks] = *(const u32x4*)(wrow + ks * 32);
  }

  // --- init: fp32 master (gh kh0 only) + publish h[-1] into slot 2 ---
  float mh[2][4] = {};
  if (!isXp && kh == 0) {
#pragma unroll
    for (int mt = 0; mt < 2; ++mt) {
      unsigned pk[4];
#pragma unroll
      for (int rg = 0; rg < 4; ++rg) {
        int bb = bg * 32 + mt * 16 + rq * 4 + rg;
        mh[mt][rg] = hidden[(long)l * 65536 + (long)bb * 512 + ch];
        pk[rg] = (unsigned)f2bf(mh[mt][rg]);
      }
#pragma unroll
      for (int rg = 0; rg < 4; ++rg) {
        unsigned prt = (unsigned)__shfl_xor((int)pk[rg], 1);
        if (!(cl & 1))
          __hip_atomic_store(
              &ringL[2 * 32768 + (bg * 32 + mt * 16 + rq * 4 + rg) * 256 + (ch >> 1)],
              pk[rg] | (prt << 16), __ATOMIC_RELAXED, __HIP_MEMORY_SCOPE_AGENT);
      }
    }
  }
  asm volatile("s_waitcnt vmcnt(0)" ::: "memory");
  __syncthreads();
  if (tid == 0)
    __hip_atomic_store(&myflags[cg], 1u, __ATOMIC_RELAXED, __HIP_MEMORY_SCOPE_AGENT);

  int sl = 0;   // t % 3
#pragma unroll 1
  for (int t = 0; t < S_; ++t) {
    const int slp = (sl == 0) ? 2 : sl - 1;   // (t-1) % 3
    // in-loop pin: wf must be materialized in regs each phase (reload illegal)
#pragma unroll
    for (int g = 0; g < 3; ++g)
#pragma unroll
      for (int ks = 0; ks < 8; ++ks) asm volatile("" : "+v"(wf[g][ks]));

    // --- layer-0 xp: stage embedding rows into sHB (flag-independent) ---
    if (isXp && l == 0) {
      int u = tid - 256;
#pragma unroll
      for (int i = 0; i < 2; ++i) {
        int task = u + i * 256;
        int row = task >> 4;
        int c0 = (task & 15) * 32;
        int tk = tok[(long)(bg * 32 + row) * 512 + t];
        const float* es = embedding + (long)tk * 512 + c0;
        u16 tmp[32];
#pragma unroll
        for (int q = 0; q < 8; ++q) {
          float4 v = *(const float4*)(es + q * 4);
          tmp[q * 4 + 0] = f2bf(v.x); tmp[q * 4 + 1] = f2bf(v.y);
          tmp[q * 4 + 2] = f2bf(v.z); tmp[q * 4 + 3] = f2bf(v.w);
        }
#pragma unroll
        for (int q = 0; q < 4; ++q) {
          int grp = (c0 >> 3) + q;
          *(u32x4*)&sHB[row * 512 + ((grp ^ (row & 7)) * 8)] = *(u32x4*)&tmp[q * 8];
        }
      }
    }
    asm volatile("" ::: "memory");
    // --- poll (per-wave minimal conditions) ---
    if (!(isXp && l == 0)) {
      const unsigned* fb;
      int tgt;
      if (isXp) { fb = flags + (l - 1) * 64 + bg * 16; tgt = t + 2; }
      else if (lane >= 32 && l < 2) { fb = flags + (l + 1) * 64 + bg * 16; tgt = t - 1; }
      else { fb = myflags; tgt = t + 1; }
      const unsigned* fp = fb + (lane & 15);
      int it = 0;
      bool ok;
      do {
        unsigned v = __hip_atomic_load(fp, __ATOMIC_RELAXED, __HIP_MEMORY_SCOPE_AGENT);
        ok = (bool)__all((int)v >= tgt);
        if (!ok) __builtin_amdgcn_s_sleep(2);
      } while (!ok && ++it < (1 << 22));
    }
    asm volatile("" ::: "memory");
    // --- stage h slices (bypass loads): gh thr 0-255 -> sHA, xp thr 256-511 -> sHB ---
    if (!isXp || l > 0) {
      const unsigned* hsrc = (!isXp ? (const unsigned*)ringL + slp * 32768
                                    : ringB + sl * 32768) + bg * 32 * 256;
      u16* dstL = !isXp ? sHA : sHB;
      int u = isXp ? tid - 256 : tid;
      u32x4 vv[8];
#pragma unroll
      for (int i = 0; i < 8; ++i) {
        int uu = u + i * 256;
        const unsigned* src = hsrc + (uu >> 6) * 256 + (uu & 63) * 4;
        asm volatile("global_load_dwordx4 %0, %1, off sc0 sc1"
                     : "=&v"(vv[i]) : "v"(src) : "memory");
      }
      asm volatile("s_waitcnt vmcnt(0)" ::: "memory");
      __builtin_amdgcn_sched_barrier(0);
#pragma unroll
      for (int i = 0; i < 8; ++i) {
        int uu = u + i * 256;
        int row = uu >> 6, c8 = uu & 63;
        *(u32x4*)&dstL[row * 512 + ((c8 ^ (row & 7)) * 8)] = vv[i];
      }
    }
    __syncthreads();                                   // B1
    // --- MFMA: 2 M-tiles x 3 gates x K-half(256), weights from registers ---
    f32x4 acc[2][3] = {};
    const u16* sH = isXp ? sHB : sHA;
#pragma unroll
    for (int mt = 0; mt < 2; ++mt) {
      const int abase = (mt * 16 + rr) * 512;
      const int axor = (mt * 16 + rr) & 7;
#pragma unroll
      for (int ks = 0; ks < 8; ++ks) {
        const int grp = kh * 32 + ks * 4 + kq;
        bf16x8 af = __builtin_bit_cast(
            bf16x8, *(const u32x4*)&sH[abase + ((grp ^ axor) * 8)]);
#pragma unroll
        for (int g = 0; g < 3; ++g)
          acc[mt][g] = __builtin_amdgcn_mfma_f32_16x16x32_bf16(
              af, __builtin_bit_cast(bf16x8, wf[g][ks]), acc[mt][g], 0, 0, 0);
      }
    }
    // --- kh=1 waves: dump partials to LDS ---
    if (kh == 1) {
#pragma unroll
      for (int mt = 0; mt < 2; ++mt)
#pragma unroll
        for (int g = 0; g < 3; ++g) {
          float* sp = &sPART[((((isXp ? 2 : 0) + nh) * 2 + mt) * 3 + g) * 272];
#pragma unroll
          for (int rg = 0; rg < 4; ++rg)
            sp[(rq * 4 + rg) * 17 + cl] = acc[mt][g][rg];
        }
    }
    __syncthreads();                                   // B2
    // --- kh=0 waves: combine; xp kh0 writes sXP ---
    if (kh == 0) {
#pragma unroll
      for (int mt = 0; mt < 2; ++mt)
#pragma unroll
        for (int g = 0; g < 3; ++g) {
          const float* sp = &sPART[((((isXp ? 2 : 0) + nh) * 2 + mt) * 3 + g) * 272];
#pragma unroll
          for (int rg = 0; rg < 4; ++rg)
            acc[mt][g][rg] += sp[(rq * 4 + rg) * 17 + cl];
        }
      if (isXp) {
#pragma unroll
        for (int mt = 0; mt < 2; ++mt)
#pragma unroll
          for (int g = 0; g < 3; ++g)
#pragma unroll
            for (int rg = 0; rg < 4; ++rg)
              sXP[(mt * 16 + rq * 4 + rg) * 101 + g * 32 + chL] =
                  acc[mt][g][rg] + bh[g];
      }
    }
    __syncthreads();                                   // B3
    // --- gates + publish (gh kh0 waves only: 128 threads cover 32b x 32ch) ---
    unsigned xsv[2][4];
    if (!isXp && kh == 0) {
#pragma unroll
      for (int mt = 0; mt < 2; ++mt) {
        unsigned pk[4];
#pragma unroll
        for (int rg = 0; rg < 4; ++rg) {
          int rloc = mt * 16 + rq * 4 + rg;
          float xr = sXP[rloc * 101 + chL];
          float xz = sXP[rloc * 101 + 32 + chL];
          float xn = sXP[rloc * 101 + 64 + chL];
          float r = 1.f / (1.f + __expf(-(xr + acc[mt][0][rg] + bh[0])));
          float z = 1.f / (1.f + __expf(-(xz + acc[mt][1][rg] + bh[1])));
          float n = tanhf(xn + r * (acc[mt][2][rg] + bh[2]));
          float h2 = (1.f - z) * n + z * mh[mt][rg];
          mh[mt][rg] = h2;
          pk[rg] = (unsigned)f2bf(h2);
        }
        xsv[mt][0] = pk[0]; xsv[mt][1] = pk[1]; xsv[mt][2] = pk[2]; xsv[mt][3] = pk[3];
#pragma unroll
        for (int rg = 0; rg < 4; ++rg) {
          unsigned prt = (unsigned)__shfl_xor((int)pk[rg], 1);
          if (!(cl & 1))
            __hip_atomic_store(
                &ringL[sl * 32768 + (bg * 32 + mt * 16 + rq * 4 + rg) * 256 + (ch >> 1)],
                pk[rg] | (prt << 16), __ATOMIC_RELAXED, __HIP_MEMORY_SCOPE_AGENT);
        }
      }
      asm volatile("s_waitcnt vmcnt(0)" ::: "memory");   // ring data at IC
    }
    __syncthreads();                                   // B4: all publishes drained
    if (tid == 0)
      __hip_atomic_store(&myflags[cg], (unsigned)(t + 2), __ATOMIC_RELAXED,
                         __HIP_MEMORY_SCOPE_AGENT);
    // l=2 output stores AFTER the flag: off the handshake critical path
    if (l == 2 && !isXp && kh == 0) {
#pragma unroll
      for (int mt = 0; mt < 2; ++mt)
#pragma unroll
        for (int rg = 0; rg < 4; ++rg) {
          int rloc = mt * 16 + rq * 4 + rg;
          xout2[((long)(bg * 32 + rloc) * 512 + t) * 512 + ch] = (u16)xsv[mt][rg];
        }
    }
    sl = (sl == 2) ? 0 : sl + 1;
  }
  if (!isXp && kh == 0) {
#pragma unroll
    for (int mt = 0; mt < 2; ++mt)
#pragma unroll
      for (int rg = 0; rg < 4; ++rg)
        hfin[(long)l * 65536 + (long)(bg * 32 + mt * 16 + rq * 4 + rg) * 512 + ch] =
            mh[mt][rg];
  }
}

extern "C" void kernel_launch(void* const* d_in, const int* in_sizes, int n_in,
                              void* d_out, int out_size, void* d_ws, size_t ws_size,
                              hipStream_t stream) {
  const int* padded    = (const int*)d_in[0];
  const float* enc     = (const float*)d_in[2];
  const float* hidden  = (const float*)d_in[3];
  const float* embedding = (const float*)d_in[4];
  const float* w_ih    = (const float*)d_in[5];
  const float* w_hh    = (const float*)d_in[6];
  const float* b_ih    = (const float*)d_in[7];
  const float* b_hh    = (const float*)d_in[8];
  const float* attn_w  = (const float*)d_in[9];
  const float* attn_b  = (const float*)d_in[10];
  const float* out_w   = (const float*)d_in[11];
  const float* out_b   = (const float*)d_in[12];

  if (ws_size < 280204288ULL) return;   // ws budget guard

  char* ws = (char*)d_ws;
  u16* W_IH   = (u16*)(ws + 0);               // 3*1536*512 bf16
  u16* W_HH   = (u16*)(ws + 4718592);
  u16* ATTN_W = (u16*)(ws + 9437184);         // 512*1024 bf16
  u16* OUT_W  = (u16*)(ws + 10485760);        // 100*512 bf16
  unsigned* FLAGS = (unsigned*)(ws + 10588160);   // 3*64 u32 (1 KB slot)
  unsigned* RING  = (unsigned*)(ws + 10589184);   // 3*3*128*256 u32 = 1.125 MB
  u16* XA     = (u16*)(ws + 11768832);        // context bf16, 64 MB
  u16* XB     = (u16*)(ws + 78877696);        // dec = layer-2 output, 64 MB
  u16* ENCT   = (u16*)(ws + 145986560);       // enc^T bf16, 64 MB
  u16* AMASK  = (u16*)(ws + 213095424);       // tanh-masked / softmax-bf16 alias, 64 MB
  u16* ATTN_BF = AMASK;

  float* out_logits = (float*)d_out;                 // 65536*100
  float* out_h      = out_logits + 6553600;          // 3*128*512
  float* out_attn   = out_h + 196608;                // 128*512*512

  zero_flags<<<1, 256, 0, stream>>>(FLAGS, 192);
  cvt_f32_bf16<<<512, 256, 0, stream>>>(w_ih, W_IH, 2359296 / 4);
  cvt_f32_bf16<<<512, 256, 0, stream>>>(w_hh, W_HH, 2359296 / 4);
  cvt_f32_bf16<<<256, 256, 0, stream>>>(attn_w, ATTN_W, 524288 / 4);
  cvt_f32_bf16<<<64, 256, 0, stream>>>(out_w, OUT_W, 51200 / 4);
  // pre-GRU: also provides the L2 scrub traffic before ring bypass ops
  transpose_enc<<<dim3(8, 8, 128), 256, 0, stream>>>(enc, ENCT);

  gru_wave<<<192, 512, 0, stream>>>(
      padded, embedding, W_IH, W_HH, b_ih, b_hh, hidden,
      RING, FLAGS, XB, out_h);

  // attention (scores GEMM converts f32 enc in staging; no ENC_BF buffer)
  gemm_xwt<1, 1><<<dim3(4, 4, 128), 256, 0, stream>>>(
      XB, nullptr, (const u16*)enc, nullptr, out_attn, nullptr,
      512, 512, 512, 262144, 262144, 262144, 0.044194173824159216f, 512);
  softmax_rows<<<16384, 256, 0, stream>>>(out_attn, ATTN_BF);
  gemm_xwt<2, 0><<<dim3(4, 4, 128), 256, 0, stream>>>(
      ATTN_BF, nullptr, ENCT, nullptr, XA, nullptr,
      512, 512, 512, 262144, 262144, 262144, 1.f, 512);
  gemm_xwt<3, 0><<<dim3(4, 512, 1), 256, 0, stream>>>(
      XB, XA, ATTN_W, attn_b, AMASK, XB,
      512, 1024, 512, 0, 0, 0, 1.f, 512);
  gemm_xwt<4, 0><<<dim3(1, 512, 1), 256, 0, stream>>>(
      AMASK, nullptr, OUT_W, out_b, d_out, XB,
      100, 512, 512, 0, 0, 0, 1.f, 100);
}

// Round 8
// 4492.126 us; speedup vs baseline: 6.8333x; 1.0471x over previous
//
#include <hip/hip_runtime.h>

// Decoder: emb -> 3-layer GRU -> scaled-dot attention over encoder -> tanh(linear) -> logits
// Round 7: xp pipelined one step ahead (sXP ping-pong) -> per-phase critical path is the
// gh own-layer IC hop only (r2's proven 3.75us structure). Ring 4 slots (WAR slack 3),
// unified t=-1 prologue phase, 3 barriers/phase, s_sleep(1) polls.
// Accepted fact: weights stream from L2 (RA won't hold them; 3 coercion attempts failed).

typedef unsigned short u16;
typedef __attribute__((ext_vector_type(8))) __bf16 bf16x8;
typedef __attribute__((ext_vector_type(4))) float f32x4;
typedef __attribute__((ext_vector_type(4))) unsigned int u32x4;

#define D_ 512
#define S_ 512
#define SE_ 512
#define B_ 128
#define V_ 100
#define TD_ 1536

__device__ __forceinline__ float bf2f(u16 v) {
  unsigned u = ((unsigned)v) << 16;
  return __builtin_bit_cast(float, u);
}
__device__ __forceinline__ u16 f2bf(float f) {
  unsigned u = __builtin_bit_cast(unsigned, f);
  u += 0x7FFF + ((u >> 16) & 1);   // RNE
  return (u16)(u >> 16);
}

// ---------------- elementwise converts ----------------
__global__ __launch_bounds__(256) void cvt_f32_bf16(const float* __restrict__ src,
                                                    u16* __restrict__ dst, long n4) {
  long i = (long)blockIdx.x * 256 + threadIdx.x;
  long stride = (long)gridDim.x * 256;
  for (; i < n4; i += stride) {
    float4 v = ((const float4*)src)[i];
    unsigned long long p = (unsigned long long)f2bf(v.x) |
                           ((unsigned long long)f2bf(v.y) << 16) |
                           ((unsigned long long)f2bf(v.z) << 32) |
                           ((unsigned long long)f2bf(v.w) << 48);
    ((unsigned long long*)dst)[i] = p;
  }
}

// zero flags at the coherence point (bypass stores - no stale-L2 window)
__global__ __launch_bounds__(256) void zero_flags(unsigned* __restrict__ f, int n) {
  int i = blockIdx.x * 256 + threadIdx.x;
  if (i < n)
    __hip_atomic_store(&f[i], 0u, __ATOMIC_RELAXED, __HIP_MEMORY_SCOPE_AGENT);
}

// enc (B,SE,D) f32 -> encT (B,D,SE) bf16
__global__ __launch_bounds__(256) void transpose_enc(const float* __restrict__ enc,
                                                     u16* __restrict__ encT) {
  __shared__ u16 tile[64][72];
  int b = blockIdx.z, d0 = blockIdx.x * 64, se0 = blockIdx.y * 64;
  const float* src = enc + (long)b * SE_ * D_;
  int t = threadIdx.x;
  int r = t >> 2, cq = (t & 3) * 16;
#pragma unroll
  for (int j = 0; j < 4; ++j) {
    float4 v = *(const float4*)(src + (long)(se0 + r) * D_ + d0 + cq + j * 4);
    tile[r][cq + j * 4 + 0] = f2bf(v.x);
    tile[r][cq + j * 4 + 1] = f2bf(v.y);
    tile[r][cq + j * 4 + 2] = f2bf(v.z);
    tile[r][cq + j * 4 + 3] = f2bf(v.w);
  }
  __syncthreads();
  u16* dst = encT + (long)b * D_ * SE_;
  u16 ov[16];
#pragma unroll
  for (int j = 0; j < 16; ++j) ov[j] = tile[cq + j][r];
  *(u32x4*)(dst + (long)(d0 + r) * SE_ + se0 + cq) = *(u32x4*)&ov[0];
  *(u32x4*)(dst + (long)(d0 + r) * SE_ + se0 + cq + 8) = *(u32x4*)&ov[8];
}

// in-place fp32 softmax over 512-wide rows + bf16 copy
__global__ __launch_bounds__(256) void softmax_rows(float* __restrict__ sc,
                                                    u16* __restrict__ abf) {
  long row = (long)blockIdx.x * 4 + (threadIdx.x >> 6);
  int lane = threadIdx.x & 63;
  float* p = sc + row * 512;
  float4 v0 = ((const float4*)p)[lane * 2];
  float4 v1 = ((const float4*)p)[lane * 2 + 1];
  float vals[8] = {v0.x, v0.y, v0.z, v0.w, v1.x, v1.y, v1.z, v1.w};
  float m = vals[0];
#pragma unroll
  for (int j = 1; j < 8; ++j) m = fmaxf(m, vals[j]);
#pragma unroll
  for (int o = 32; o; o >>= 1) m = fmaxf(m, __shfl_xor(m, o, 64));
  float s = 0.f;
#pragma unroll
  for (int j = 0; j < 8; ++j) { vals[j] = __expf(vals[j] - m); s += vals[j]; }
#pragma unroll
  for (int o = 32; o; o >>= 1) s += __shfl_xor(s, o, 64);
  float inv = 1.f / s;
  u16 ob[8];
#pragma unroll
  for (int j = 0; j < 8; ++j) { vals[j] *= inv; ob[j] = f2bf(vals[j]); }
  float4 w0 = {vals[0], vals[1], vals[2], vals[3]};
  float4 w1 = {vals[4], vals[5], vals[6], vals[7]};
  ((float4*)p)[lane * 2] = w0;
  ((float4*)p)[lane * 2 + 1] = w1;
  *(u32x4*)(abf + row * 512 + lane * 8) = *(u32x4*)ob;
}

// ---------------- generic C = A(M,K) @ W(N,K)^T, bf16 in / f32 acc ----------------
// MODE 1: *scale -> f32 batched (scores; WF32: W is f32, cvt in staging)
// MODE 2: -> bf16 batched (context) MODE 3: split-K A, tanh(+bias)*mask -> bf16
// MODE 4: (+bias)*mask -> f32, col<N (logits)
template <int MODE, int WF32>
__global__ __launch_bounds__(256) void gemm_xwt(
    const u16* __restrict__ A1, const u16* __restrict__ A2, const u16* __restrict__ W,
    const float* __restrict__ bias, void* __restrict__ Cout, const u16* __restrict__ maskSrc,
    int N, int K, int K1, long sAb, long sWb, long sCb, float scale, int ldc) {
  __shared__ u16 sA[128][32];
  __shared__ u16 sW_[128][32];
  int bz = blockIdx.z;
  int n0 = blockIdx.x * 128, m0 = blockIdx.y * 128;
  const u16* Ab = A1 + (long)bz * sAb;
  int t = threadIdx.x, wave = t >> 6, lane = t & 63;
  int wm = (wave >> 1) * 64, wn = (wave & 1) * 64;
  f32x4 acc[4][4] = {};
  for (int kk = 0; kk < K; kk += 32) {
#pragma unroll
    for (int i = 0; i < 2; ++i) {
      int id = t + i * 256;
      int row = id >> 2, c8 = (id & 3) * 8;
      const u16* src;
      if (MODE == 3 && kk >= K1)
        src = A2 + (long)(m0 + row) * (K - K1) + (kk - K1) + c8;
      else
        src = Ab + (long)(m0 + row) * K1 + kk + c8;
      *(u32x4*)&sA[row][c8] = *(const u32x4*)src;
    }
#pragma unroll
    for (int i = 0; i < 2; ++i) {
      int id = t + i * 256;
      int row = id >> 2, c8 = (id & 3) * 8;
      if (WF32) {
        const float* wsrc = ((const float*)W) + (long)bz * sWb + (long)(n0 + row) * K + kk + c8;
        float4 va = *(const float4*)wsrc;
        float4 vb = *(const float4*)(wsrc + 4);
        u16 tmp[8] = {f2bf(va.x), f2bf(va.y), f2bf(va.z), f2bf(va.w),
                      f2bf(vb.x), f2bf(vb.y), f2bf(vb.z), f2bf(vb.w)};
        *(u32x4*)&sW_[row][c8] = *(u32x4*)tmp;
      } else {
        u32x4 v = {0u, 0u, 0u, 0u};
        if (n0 + row < N) v = *(const u32x4*)(W + (long)bz * sWb + (long)(n0 + row) * K + kk + c8);
        *(u32x4*)&sW_[row][c8] = v;
      }
    }
    __syncthreads();
    int k8 = (lane >> 4) * 8, rr = lane & 15;
    bf16x8 wf[4];
#pragma unroll
    for (int nt = 0; nt < 4; ++nt)
      wf[nt] = __builtin_bit_cast(bf16x8, *(const u32x4*)&sW_[wn + nt * 16 + rr][k8]);
#pragma unroll
    for (int mt = 0; mt < 4; ++mt) {
      bf16x8 af = __builtin_bit_cast(bf16x8, *(const u32x4*)&sA[wm + mt * 16 + rr][k8]);
#pragma unroll
      for (int nt = 0; nt < 4; ++nt)
        acc[mt][nt] = __builtin_amdgcn_mfma_f32_16x16x32_bf16(af, wf[nt], acc[mt][nt], 0, 0, 0);
    }
    __syncthreads();
  }
  int rq = (lane >> 4) * 4, cl = lane & 15;
#pragma unroll
  for (int mt = 0; mt < 4; ++mt) {
#pragma unroll
    for (int nt = 0; nt < 4; ++nt) {
#pragma unroll
      for (int rg = 0; rg < 4; ++rg) {
        int row = m0 + wm + mt * 16 + rq + rg;
        int col = n0 + wn + nt * 16 + cl;
        float v = acc[mt][nt][rg];
        if (MODE == 1) {
          ((float*)Cout)[(long)bz * sCb + (long)row * ldc + col] = v * scale;
        } else if (MODE == 2) {
          ((u16*)Cout)[(long)bz * sCb + (long)row * ldc + col] = f2bf(v);
        } else if (MODE == 3) {
          float mk = (bf2f(maskSrc[(long)row * D_]) != 0.f) ? 1.f : 0.f;
          ((u16*)Cout)[(long)row * ldc + col] = f2bf(tanhf(v + bias[col]) * mk);
        } else {
          if (col < N) {
            float mk = (bf2f(maskSrc[(long)row * D_]) != 0.f) ? 1.f : 0.f;
            ((float*)Cout)[(long)row * ldc + col] = (v + bias[col]) * mk;
          }
        }
      }
    }
  }
}

// ---------------- wavefront-pipelined 3-layer GRU, xp one step ahead ----------------
// grid 192 = l(3) x bg(4) x cg(16); 512 thr = 8 waves (gh: nh x kh, xp: nh x kh).
// Phase t: gh consumes sXP[t&1] (written last phase); xp prepares xp[t+1] into
// sXP[(t+1)&1] (poll below>=t+3, stage h_below[t+1]). Unified t=-1 prologue phase:
// gh publishes h[-1] (slot 3), xp computes xp[0].
// ring[l]: 4 slots x [128][256] u32 packed bf16 pairs, bypass (sc0 sc1) ops.
// flags[l][bg][cg]=t+2 after phase t. Polls: gh lane<32 own>=t+1, gh lane>=32
// above>=t-3 (l<2, WAR slack 3); xp below>=t+3 (l>0).
__global__ __launch_bounds__(512, 1) void gru_wave(
    const int* __restrict__ tok, const float* __restrict__ embedding,
    const u16* __restrict__ wih_all, const u16* __restrict__ whh_all,
    const float* __restrict__ bih_all, const float* __restrict__ bhh_all,
    const float* __restrict__ hidden,
    unsigned* __restrict__ ring, unsigned* __restrict__ flags,
    u16* __restrict__ xout2, float* __restrict__ hfin) {
  __shared__ u16 sHA[32 * 512];
  __shared__ u16 sHB[32 * 512];
  __shared__ float sXP[2][32 * 101];
  __shared__ float sPART[24 * 272];
  const int bid = blockIdx.x;
  const int l = bid >> 6;
  const int bg = (bid >> 4) & 3;
  const int cg = bid & 15;
  const int tid = threadIdx.x;
  const int wave = tid >> 6;          // 0..7
  const bool isXp = wave >= 4;
  const int nh = (wave >> 1) & 1;
  const int kh = wave & 1;
  const int lane = tid & 63;
  const int rr = lane & 15, kq = lane >> 4;
  const int cl = rr, rq = kq;
  const int chL = nh * 16 + cl;
  const int ch = cg * 32 + chL;       // this thread's output channel
  unsigned* myflags = flags + l * 64 + bg * 16;
  const unsigned* aboveflags = (l < 2) ? flags + (l + 1) * 64 + bg * 16 : myflags;
  const unsigned* belowflags = (l > 0) ? flags + (l - 1) * 64 + bg * 16 : myflags;
  const u16* Wsrc = (isXp ? wih_all : whh_all) + (long)l * 786432;
  const float* bsrc = (isXp ? bih_all : bhh_all) + l * 1536;
  float bh[3];
#pragma unroll
  for (int g = 0; g < 3; ++g) bh[g] = bsrc[g * 512 + ch];
  unsigned* ringL = ring + l * 4 * 32768;
  const unsigned* ringB = ring + (l - 1) * 4 * 32768;   // valid for l>0

  // --- load this wave's K-half weight fragments: 24 x u32x4 = 96 VGPRs ---
  u32x4 wf[3][8];
#pragma unroll
  for (int g = 0; g < 3; ++g) {
    const u16* wrow =
        Wsrc + ((long)(g * 512 + cg * 32 + nh * 16 + rr)) * 512 + kh * 256 + kq * 8;
#pragma unroll
    for (int ks = 0; ks < 8; ++ks) wf[g][ks] = *(const u32x4*)(wrow + ks * 32);
  }

  // --- fp32 master h (gh kh0 only) ---
  float mh[2][4] = {};
  if (!isXp && kh == 0) {
#pragma unroll
    for (int mt = 0; mt < 2; ++mt)
#pragma unroll
      for (int rg = 0; rg < 4; ++rg)
        mh[mt][rg] =
            hidden[(long)l * 65536 + (long)(bg * 32 + mt * 16 + rq * 4 + rg) * 512 + ch];
  }

  auto poll = [&](const unsigned* fb, int tgt) {
    const unsigned* fp = fb + (lane & 15);
    int it = 0;
    bool ok;
    do {
      unsigned v = __hip_atomic_load(fp, __ATOMIC_RELAXED, __HIP_MEMORY_SCOPE_AGENT);
      ok = (bool)__all((int)v >= tgt);
      if (!ok) __builtin_amdgcn_s_sleep(1);
    } while (!ok && ++it < (1 << 22));
  };

#pragma unroll 1
  for (int t = -1; t < S_; ++t) {
    const bool doXp = isXp && (t < S_ - 1);
    // in-loop pin (cheap; keeps wf materialization near the top of the phase)
#pragma unroll
    for (int g = 0; g < 3; ++g)
#pragma unroll
      for (int ks = 0; ks < 8; ++ks) asm volatile("" : "+v"(wf[g][ks]));

    // --- layer-0 xp: stage embedding rows for step t+1 (flag-independent) ---
    if (doXp && l == 0) {
      int u = tid - 256;
#pragma unroll
      for (int i = 0; i < 2; ++i) {
        int task = u + i * 256;
        int row = task >> 4;
        int c0 = (task & 15) * 32;
        int tk = tok[(long)(bg * 32 + row) * 512 + (t + 1)];
        const float* es = embedding + (long)tk * 512 + c0;
        u16 tmp[32];
#pragma unroll
        for (int q = 0; q < 8; ++q) {
          float4 v = *(const float4*)(es + q * 4);
          tmp[q * 4 + 0] = f2bf(v.x); tmp[q * 4 + 1] = f2bf(v.y);
          tmp[q * 4 + 2] = f2bf(v.z); tmp[q * 4 + 3] = f2bf(v.w);
        }
#pragma unroll
        for (int q = 0; q < 4; ++q) {
          int grp = (c0 >> 3) + q;
          *(u32x4*)&sHB[row * 512 + ((grp ^ (row & 7)) * 8)] = *(u32x4*)&tmp[q * 8];
        }
      }
    }
    asm volatile("" ::: "memory");
    // --- polls (per-wave minimal conditions) ---
    if (!isXp) {
      if (lane >= 32 && l < 2) poll(aboveflags, t - 3);   // ring WAR back-pressure
      else poll(myflags, t + 1);                          // siblings published h[t-1]
    } else if (doXp && l > 0) {
      poll(belowflags, t + 3);                            // h_below[t+1] available
    }
    asm volatile("" ::: "memory");
    // --- stage h slices (bypass loads from ring) ---
    if (!isXp && t >= 0) {
      const unsigned* hsrc = ringL + ((t + 3) & 3) * 32768 + bg * 32 * 256;
      u32x4 vv[8];
#pragma unroll
      for (int i = 0; i < 8; ++i) {
        int uu = tid + i * 256;
        const unsigned* src = hsrc + (uu >> 6) * 256 + (uu & 63) * 4;
        asm volatile("global_load_dwordx4 %0, %1, off sc0 sc1"
                     : "=&v"(vv[i]) : "v"(src) : "memory");
      }
      asm volatile("s_waitcnt vmcnt(0)" ::: "memory");
      __builtin_amdgcn_sched_barrier(0);
#pragma unroll
      for (int i = 0; i < 8; ++i) {
        int uu = tid + i * 256;
        int row = uu >> 6, c8 = uu & 63;
        *(u32x4*)&sHA[row * 512 + ((c8 ^ (row & 7)) * 8)] = vv[i];
      }
    } else if (doXp && l > 0) {
      const unsigned* hsrc = ringB + ((t + 1) & 3) * 32768 + bg * 32 * 256;
      u32x4 vv[8];
#pragma unroll
      for (int i = 0; i < 8; ++i) {
        int uu = (tid - 256) + i * 256;
        const unsigned* src = hsrc + (uu >> 6) * 256 + (uu & 63) * 4;
        asm volatile("global_load_dwordx4 %0, %1, off sc0 sc1"
                     : "=&v"(vv[i]) : "v"(src) : "memory");
      }
      asm volatile("s_waitcnt vmcnt(0)" ::: "memory");
      __builtin_amdgcn_sched_barrier(0);
#pragma unroll
      for (int i = 0; i < 8; ++i) {
        int uu = (tid - 256) + i * 256;
        int row = uu >> 6, c8 = uu & 63;
        *(u32x4*)&sHB[row * 512 + ((c8 ^ (row & 7)) * 8)] = vv[i];
      }
    }
    __syncthreads();                                   // B1
    // --- MFMA: 2 M-tiles x 3 gates x K-half(256) ---
    f32x4 acc[2][3] = {};
    const bool doMM = isXp ? doXp : (t >= 0);
    if (doMM) {
      const u16* sH = isXp ? sHB : sHA;
#pragma unroll
      for (int mt = 0; mt < 2; ++mt) {
        const int abase = (mt * 16 + rr) * 512;
        const int axor = (mt * 16 + rr) & 7;
#pragma unroll
        for (int ks = 0; ks < 8; ++ks) {
          const int grp = kh * 32 + ks * 4 + kq;
          bf16x8 af = __builtin_bit_cast(
              bf16x8, *(const u32x4*)&sH[abase + ((grp ^ axor) * 8)]);
#pragma unroll
          for (int g = 0; g < 3; ++g)
            acc[mt][g] = __builtin_amdgcn_mfma_f32_16x16x32_bf16(
                af, __builtin_bit_cast(bf16x8, wf[g][ks]), acc[mt][g], 0, 0, 0);
        }
      }
      if (kh == 1) {
#pragma unroll
        for (int mt = 0; mt < 2; ++mt)
#pragma unroll
          for (int g = 0; g < 3; ++g) {
            float* sp = &sPART[((((isXp ? 2 : 0) + nh) * 2 + mt) * 3 + g) * 272];
#pragma unroll
            for (int rg = 0; rg < 4; ++rg)
              sp[(rq * 4 + rg) * 17 + cl] = acc[mt][g][rg];
          }
      }
    }
    __syncthreads();                                   // B2
    if (doMM && kh == 0) {
#pragma unroll
      for (int mt = 0; mt < 2; ++mt)
#pragma unroll
        for (int g = 0; g < 3; ++g) {
          const float* sp = &sPART[((((isXp ? 2 : 0) + nh) * 2 + mt) * 3 + g) * 272];
#pragma unroll
          for (int rg = 0; rg < 4; ++rg)
            acc[mt][g][rg] += sp[(rq * 4 + rg) * 17 + cl];
        }
      if (isXp) {
        float* xpd = sXP[(t + 1) & 1];
#pragma unroll
        for (int mt = 0; mt < 2; ++mt)
#pragma unroll
          for (int g = 0; g < 3; ++g)
#pragma unroll
            for (int rg = 0; rg < 4; ++rg)
              xpd[(mt * 16 + rq * 4 + rg) * 101 + g * 32 + chL] =
                  acc[mt][g][rg] + bh[g];
      }
    }
    // --- gh gates (reads sXP[t&1], written at phase t-1) + publish slot t&3 ---
    unsigned xsv[2][4];
    if (!isXp && kh == 0) {
      const float* xps = sXP[t & 1];
#pragma unroll
      for (int mt = 0; mt < 2; ++mt) {
        unsigned pk[4];
#pragma unroll
        for (int rg = 0; rg < 4; ++rg) {
          float h2;
          if (t >= 0) {
            int rloc = mt * 16 + rq * 4 + rg;
            float xr = xps[rloc * 101 + chL];
            float xz = xps[rloc * 101 + 32 + chL];
            float xn = xps[rloc * 101 + 64 + chL];
            float r = 1.f / (1.f + __expf(-(xr + acc[mt][0][rg] + bh[0])));
            float z = 1.f / (1.f + __expf(-(xz + acc[mt][1][rg] + bh[1])));
            float n = tanhf(xn + r * (acc[mt][2][rg] + bh[2]));
            h2 = (1.f - z) * n + z * mh[mt][rg];
            mh[mt][rg] = h2;
          } else {
            h2 = mh[mt][rg];   // t=-1: publish initial hidden state
          }
          pk[rg] = (unsigned)f2bf(h2);
        }
        xsv[mt][0] = pk[0]; xsv[mt][1] = pk[1]; xsv[mt][2] = pk[2]; xsv[mt][3] = pk[3];
#pragma unroll
        for (int rg = 0; rg < 4; ++rg) {
          unsigned prt = (unsigned)__shfl_xor((int)pk[rg], 1);
          if (!(cl & 1))
            __hip_atomic_store(
                &ringL[(t & 3) * 32768 + (bg * 32 + mt * 16 + rq * 4 + rg) * 256 + (ch >> 1)],
                pk[rg] | (prt << 16), __ATOMIC_RELAXED, __HIP_MEMORY_SCOPE_AGENT);
        }
      }
      asm volatile("s_waitcnt vmcnt(0)" ::: "memory");   // ring data at IC
    }
    __syncthreads();                                   // B3: publishes + sXP write done
    if (tid == 0)
      __hip_atomic_store(&myflags[cg], (unsigned)(t + 2), __ATOMIC_RELAXED,
                         __HIP_MEMORY_SCOPE_AGENT);
    // l=2 output stores AFTER the flag: off the handshake critical path
    if (l == 2 && t >= 0 && !isXp && kh == 0) {
#pragma unroll
      for (int mt = 0; mt < 2; ++mt)
#pragma unroll
        for (int rg = 0; rg < 4; ++rg) {
          int rloc = mt * 16 + rq * 4 + rg;
          xout2[((long)(bg * 32 + rloc) * 512 + t) * 512 + ch] = (u16)xsv[mt][rg];
        }
    }
  }
  if (!isXp && kh == 0) {
#pragma unroll
    for (int mt = 0; mt < 2; ++mt)
#pragma unroll
      for (int rg = 0; rg < 4; ++rg)
        hfin[(long)l * 65536 + (long)(bg * 32 + mt * 16 + rq * 4 + rg) * 512 + ch] =
            mh[mt][rg];
  }
}

extern "C" void kernel_launch(void* const* d_in, const int* in_sizes, int n_in,
                              void* d_out, int out_size, void* d_ws, size_t ws_size,
                              hipStream_t stream) {
  const int* padded    = (const int*)d_in[0];
  const float* enc     = (const float*)d_in[2];
  const float* hidden  = (const float*)d_in[3];
  const float* embedding = (const float*)d_in[4];
  const float* w_ih    = (const float*)d_in[5];
  const float* w_hh    = (const float*)d_in[6];
  const float* b_ih    = (const float*)d_in[7];
  const float* b_hh    = (const float*)d_in[8];
  const float* attn_w  = (const float*)d_in[9];
  const float* attn_b  = (const float*)d_in[10];
  const float* out_w   = (const float*)d_in[11];
  const float* out_b   = (const float*)d_in[12];

  if (ws_size < 280597504ULL) return;   // ws budget guard

  char* ws = (char*)d_ws;
  u16* W_IH   = (u16*)(ws + 0);               // 3*1536*512 bf16
  u16* W_HH   = (u16*)(ws + 4718592);
  u16* ATTN_W = (u16*)(ws + 9437184);         // 512*1024 bf16
  u16* OUT_W  = (u16*)(ws + 10485760);        // 100*512 bf16
  unsigned* FLAGS = (unsigned*)(ws + 10588160);   // 3*64 u32 (1 KB slot)
  unsigned* RING  = (unsigned*)(ws + 10589184);   // 3*4*128*256 u32 = 1.5 MB
  u16* XA     = (u16*)(ws + 12162048);        // context bf16, 64 MB
  u16* XB     = (u16*)(ws + 79270912);        // dec = layer-2 output, 64 MB
  u16* ENCT   = (u16*)(ws + 146379776);       // enc^T bf16, 64 MB
  u16* AMASK  = (u16*)(ws + 213488640);       // tanh-masked / softmax-bf16 alias, 64 MB
  u16* ATTN_BF = AMASK;

  float* out_logits = (float*)d_out;                 // 65536*100
  float* out_h      = out_logits + 6553600;          // 3*128*512
  float* out_attn   = out_h + 196608;                // 128*512*512

  zero_flags<<<1, 256, 0, stream>>>(FLAGS, 192);
  cvt_f32_bf16<<<512, 256, 0, stream>>>(w_ih, W_IH, 2359296 / 4);
  cvt_f32_bf16<<<512, 256, 0, stream>>>(w_hh, W_HH, 2359296 / 4);
  cvt_f32_bf16<<<256, 256, 0, stream>>>(attn_w, ATTN_W, 524288 / 4);
  cvt_f32_bf16<<<64, 256, 0, stream>>>(out_w, OUT_W, 51200 / 4);
  // pre-GRU: also provides the L2 scrub traffic before ring bypass ops
  transpose_enc<<<dim3(8, 8, 128), 256, 0, stream>>>(enc, ENCT);

  gru_wave<<<192, 512, 0, stream>>>(
      padded, embedding, W_IH, W_HH, b_ih, b_hh, hidden,
      RING, FLAGS, XB, out_h);

  // attention (scores GEMM converts f32 enc in staging; no ENC_BF buffer)
  gemm_xwt<1, 1><<<dim3(4, 4, 128), 256, 0, stream>>>(
      XB, nullptr, (const u16*)enc, nullptr, out_attn, nullptr,
      512, 512, 512, 262144, 262144, 262144, 0.044194173824159216f, 512);
  softmax_rows<<<16384, 256, 0, stream>>>(out_attn, ATTN_BF);
  gemm_xwt<2, 0><<<dim3(4, 4, 128), 256, 0, stream>>>(
      ATTN_BF, nullptr, ENCT, nullptr, XA, nullptr,
      512, 512, 512, 262144, 262144, 262144, 1.f, 512);
  gemm_xwt<3, 0><<<dim3(4, 512, 1), 256, 0, stream>>>(
      XB, XA, ATTN_W, attn_b, AMASK, XB,
      512, 1024, 512, 0, 0, 0, 1.f, 512);
  gemm_xwt<4, 0><<<dim3(1, 512, 1), 256, 0, stream>>>(
      AMASK, nullptr, OUT_W, out_b, d_out, XB,
      100, 512, 512, 0, 0, 0, 1.f, 100);
}